// Round 9
// baseline (1174.791 us; speedup 1.0000x reference)
//
#include <hip/hip_runtime.h>
#include <hip/hip_bf16.h>

typedef __attribute__((ext_vector_type(8))) short short8;
typedef __attribute__((ext_vector_type(4))) short shortx4;
typedef __attribute__((ext_vector_type(4))) float floatx4;
typedef __attribute__((ext_vector_type(16))) float floatx16;

#define F2BF __float2bfloat16
#define BF2F __bfloat162float

// ---------------- workspace layout (byte offsets), total ~112.0 MiB ----------------
#define WS_W4R2   0UL
#define WS_WRO2   9437184UL
#define WS_WRO1   11796480UL
#define WS_Y1     16515072UL
#define WS_Y2     50069504UL
#define WS_W4R1   50069504UL
#define WS_A      68943872UL
#define WS_WTB    77332480UL
#define WS_SRCB   77856768UL
#define WS_STATS  117178368UL
#define WS_ANS    117186560UL
#define WS_WORD   117256192UL
#define WS_WORD2  117272576UL
#define WS_EFFW   117346336UL
#define WS_EFFB   117420064UL

#define OUT_LOGITS 131072
#define OUT_SRC    131256

__device__ __forceinline__ float inp(const void* p, long i, int isbf) {
    return isbf ? BF2F(((const __hip_bfloat16*)p)[i]) : ((const float*)p)[i];
}
__device__ __forceinline__ void outw(void* p, long i, float v, int isbf) {
    if (isbf) ((__hip_bfloat16*)p)[i] = F2BF(v);
    else      ((float*)p)[i] = v;
}
__device__ __forceinline__ float bfbits2f(short s) {
    unsigned int u = ((unsigned int)(unsigned short)s) << 16;
    float f; __builtin_memcpy(&f, &u, 4); return f;
}
__device__ __forceinline__ short f2bfbits(float f) {
    __hip_bfloat16 h = F2BF(f);
    short s; __builtin_memcpy(&s, &h, 2); return s;
}

__device__ __forceinline__ int detect_bf(const void* img) {
    const unsigned short* u = (const unsigned short*)img;
    int l = threadIdx.x & 63;
    int c = 0;
#pragma unroll
    for (int k = 0; k < 8; ++k) {
        int e = (u[(l * 8 + k) * 2] >> 7) & 0xFF;
        c += (e >= 100 && e <= 150) ? 1 : 0;
    }
    for (int off = 32; off; off >>= 1) c += __shfl_xor(c, off, 64);
    return c > 307;
}

__device__ __forceinline__ float pe_val(int n, int c) {
    float pos = (c < 256) ? (float)(n & 31) : (float)(n >> 5);
    int i = ((c < 256) ? c : (c - 256)) >> 1;
    float ang = pos * expf(-0.0719557841560639f * (float)i);
    return (c & 1) ? cosf(ang) : sinf(ang);
}

// ---- fused prep (+ stats zeroing block) ----
// W4 layout (fragment-contiguous): [tap][cc(16)][cog(Cout4/32)][ksub(2)][lane(64)][8ci]
__global__ void k_pre(const void* __restrict__ img, const void* __restrict__ cw1,
                      const void* __restrict__ cw2, const void* __restrict__ Wt,
                      __hip_bfloat16* __restrict__ A,
                      __hip_bfloat16* __restrict__ W4R1, __hip_bfloat16* __restrict__ W4R2,
                      __hip_bfloat16* __restrict__ WRo1, __hip_bfloat16* __restrict__ WRo2,
                      __hip_bfloat16* __restrict__ WTB, float* __restrict__ STZ) {
    int isbf = detect_bf(img);
    int bid = blockIdx.x, tid = threadIdx.x;
    __shared__ float LS[2304];
    if (bid < 4096) {
        int nt = bid & 31, ct = (bid >> 5) & 15, b = bid >> 9;
        int tx = tid & 31, ty = tid >> 5;
        int c0 = ct * 32, n0 = nt * 32;
        for (int j = 0; j < 4; ++j) {
            int c = c0 + ty + j * 8;
            LS[(ty + j * 8) * 33 + tx] = inp(img, ((long)(b * 512 + c)) * 1024 + n0 + tx, isbf);
        }
        __syncthreads();
        for (int j = 0; j < 4; ++j) {
            int n = n0 + ty + j * 8, c = c0 + tx;
            A[((long)(b * 1024 + n)) * 512 + c] = F2BF(LS[tx * 33 + ty + j * 8] + pe_val(n, c));
        }
    } else if (bid < 5632) {
        int bb = bid - 4096;
        const void* w; __hip_bfloat16 *w4, *wo; int Cout, r0;
        if (bb < 1024) { w = cw1; w4 = W4R1; wo = WRo1; Cout = 512; r0 = bb * 256; }
        else           { w = cw2; w4 = W4R2; wo = WRo2; Cout = 256; r0 = (bb - 1024) * 256; }
        int Cout4 = Cout << 2;
        int G = Cout4 >> 5;
        int co = r0 >> 9, ci0 = r0 & 511;
        for (int e = tid; e < 2304; e += 256) LS[e] = inp(w, (long)r0 * 9 + e, isbf);
        __syncthreads();
        int ci = ci0 + tid;
        int cc = ci >> 5, cw = ci & 31;
        int ksub = (ci >> 4) & 1, hic = (ci >> 3) & 1, ee = ci & 7;
        float w9[9];
#pragma unroll
        for (int t = 0; t < 9; ++t) w9[t] = LS[tid * 9 + t];
#pragma unroll
        for (int t = 0; t < 9; ++t)
            wo[((long)(t * 16 + cc) * Cout + co) * 32 + cw] = F2BF(w9[t]);
        const float BY[2][3][3] = {{{0.75f, 0.25f, 0.f}, {0.25f, 0.75f, 0.75f}, {0.f, 0.f, 0.25f}},
                                   {{0.25f, 0.f, 0.f},  {0.75f, 0.75f, 0.25f}, {0.f, 0.25f, 0.75f}}};
#pragma unroll
        for (int p = 0; p < 4; ++p) {
            int py = p >> 1, px = p & 1;
            int co4 = p * Cout + co;
            int cog = co4 >> 5, l31c = co4 & 31;
#pragma unroll
            for (int dy = 0; dy < 3; ++dy)
#pragma unroll
            for (int dx = 0; dx < 3; ++dx) {
                float v = 0.f;
#pragma unroll
                for (int ky = 0; ky < 3; ++ky)
#pragma unroll
                for (int kx = 0; kx < 3; ++kx)
                    v += BY[py][dy][ky] * BY[px][dx][kx] * w9[ky * 3 + kx];
                long fi = ((((long)((dy * 3 + dx) * 16 + cc) * G + cog) * 2 + ksub) * 64
                           + hic * 32 + l31c) * 8 + ee;
                w4[fi] = F2BF(v);
            }
        }
    } else if (bid < 5888) {
        for (int i = (bid - 5632) * 256 + tid; i < 512 * 512; i += 256 * 256)
            WTB[i] = F2BF(inp(Wt, i, isbf));
    } else {
        for (int i = tid; i < 6144; i += 256) STZ[i] = 0.f;   // stats + ANS zero
    }
}

// ---- MFMA GEMM + fused epilogue (reg-prefetch staging) ----
__global__ __launch_bounds__(256) void k_gemm1(const __hip_bfloat16* __restrict__ A,
                                               const __hip_bfloat16* __restrict__ Bw,
                                               __hip_bfloat16* __restrict__ srcB,
                                               void* __restrict__ dst,
                                               float* __restrict__ ANS,
                                               const void* __restrict__ img) {
    int isbf = detect_bf(img);
    __shared__ __align__(16) __hip_bfloat16 As[128 * 32];
    __shared__ __align__(16) __hip_bfloat16 Bs[128 * 32];
    int m0 = blockIdx.x * 128, n0 = blockIdx.y * 128;
    int tid = threadIdx.x;
    int wave = tid >> 6, l = tid & 63, lm = l & 15, q = l >> 4;
    int wm = wave & 1, wn = wave >> 1;
    int m_0 = tid >> 2, qq0 = tid & 3;
    int m_1 = (tid + 256) >> 2, qq1 = qq0;
    const __hip_bfloat16* aA0 = A + ((long)(m0 + m_0)) * 512 + qq0 * 8;
    const __hip_bfloat16* aB0 = Bw + ((long)(n0 + m_0)) * 512 + qq0 * 8;
    const __hip_bfloat16* aA1 = A + ((long)(m0 + m_1)) * 512 + qq1 * 8;
    const __hip_bfloat16* aB1 = Bw + ((long)(n0 + m_1)) * 512 + qq1 * 8;
    int wA0 = m_0 * 32 + qq0 * 8, wA1 = m_1 * 32 + qq1 * 8;
    short8 rA0 = *(const short8*)(aA0), rB0 = *(const short8*)(aB0);
    short8 rA1 = *(const short8*)(aA1), rB1 = *(const short8*)(aB1);
    floatx4 zero4 = {0.f, 0.f, 0.f, 0.f};
    floatx4 acc[4][4];
    for (int i = 0; i < 4; ++i) for (int j = 0; j < 4; ++j) acc[i][j] = zero4;
    for (int k0 = 0; k0 < 512; k0 += 32) {
        __syncthreads();
        *(short8*)(As + wA0) = rA0; *(short8*)(Bs + wA0) = rB0;
        *(short8*)(As + wA1) = rA1; *(short8*)(Bs + wA1) = rB1;
        __syncthreads();
        if (k0 < 480) {
            rA0 = *(const short8*)(aA0 + k0 + 32); rB0 = *(const short8*)(aB0 + k0 + 32);
            rA1 = *(const short8*)(aA1 + k0 + 32); rB1 = *(const short8*)(aB1 + k0 + 32);
        }
        short8 af[4], bfv[4];
#pragma unroll
        for (int t = 0; t < 4; ++t) af[t] = *(short8*)(As + (wm * 64 + t * 16 + lm) * 32 + q * 8);
#pragma unroll
        for (int t = 0; t < 4; ++t) bfv[t] = *(short8*)(Bs + (wn * 64 + t * 16 + lm) * 32 + q * 8);
#pragma unroll
        for (int i = 0; i < 4; ++i)
#pragma unroll
            for (int j = 0; j < 4; ++j)
                acc[i][j] = __builtin_amdgcn_mfma_f32_16x16x32_bf16(af[i], bfv[j], acc[i][j], 0, 0, 0);
    }
    int b = m0 >> 10, hw0 = m0 & 1023;
    float cs[4] = {0.f, 0.f, 0.f, 0.f};
#pragma unroll
    for (int i = 0; i < 4; ++i)
#pragma unroll
        for (int j = 0; j < 4; ++j) {
            int mrow = wm * 64 + i * 16 + q * 4;
            int n = n0 + wn * 64 + j * 16 + lm;
            long mg = (long)(m0 + mrow);
#pragma unroll
            for (int r = 0; r < 4; ++r) {
                float v = acc[i][j][r];
                srcB[(mg + r) * 512 + n] = F2BF(v);
                cs[j] += v;
            }
            long obase = (long)OUT_SRC + ((long)(b * 512 + n)) * 1024 + hw0 + mrow;
            if (isbf) {
                shortx4 pk = { f2bfbits(acc[i][j][0]), f2bfbits(acc[i][j][1]),
                               f2bfbits(acc[i][j][2]), f2bfbits(acc[i][j][3]) };
                *(shortx4*)((__hip_bfloat16*)dst + obase) = pk;
            } else {
                floatx4 pk = { acc[i][j][0], acc[i][j][1], acc[i][j][2], acc[i][j][3] };
                *(floatx4*)((float*)dst + obase) = pk;
            }
        }
#pragma unroll
    for (int j = 0; j < 4; ++j) {
        cs[j] += __shfl_xor(cs[j], 16);
        cs[j] += __shfl_xor(cs[j], 32);
    }
    __syncthreads();
    float* CS = (float*)Bs;
    if (wm == 1 && q == 0) {
#pragma unroll
        for (int j = 0; j < 4; ++j) CS[wn * 64 + j * 16 + lm] = cs[j];
    }
    __syncthreads();
    if (wm == 0 && q == 0) {
#pragma unroll
        for (int j = 0; j < 4; ++j) {
            int n = n0 + wn * 64 + j * 16 + lm;
            atomicAdd(ANS + b * 512 + n, cs[j] + CS[wn * 64 + j * 16 + lm]);
        }
    }
}

// ---- k_head: ansvec + word/qa + hid + logits fused (grid = 8, one block per b) ----
__global__ void k_head(const float* __restrict__ ANS, const void* __restrict__ lw,
                       const void* __restrict__ lb, const void* __restrict__ state,
                       float* __restrict__ word,
                       const void* __restrict__ w1, const void* __restrict__ b1,
                       const void* __restrict__ w2, const void* __restrict__ b2,
                       const void* __restrict__ lw2, const void* __restrict__ lb2,
                       const void* __restrict__ ew, const void* __restrict__ ebias,
                       void* __restrict__ out, const void* __restrict__ img) {
    int isbf = detect_bf(img);
    int b = blockIdx.x, tid = threadIdx.x;
    __shared__ float L[1024];
    __shared__ float aL[512];
    __shared__ float av[512];
    __shared__ float red[256];
    __shared__ float hidL[256];
    __shared__ float gates[8];
    __shared__ float feat[128];
    // ---- ansvec ----
    aL[tid] = ANS[b * 512 + tid] * (1.f / 1024.f);
    aL[tid + 256] = ANS[b * 512 + tid + 256] * (1.f / 1024.f);
    L[tid] = inp(state, b * 512 + tid, isbf);
    L[tid + 256] = inp(state, b * 512 + tid + 256, isbf);
    __syncthreads();
    int cl = tid & 3;
    for (int dt = 0; dt < 8; ++dt) {
        int d = dt * 64 + (tid >> 2);
        float acc = 0.f;
        for (int k = 0; k < 128; ++k) {
            int c = cl + 4 * k;
            acc += aL[c] * inp(lw, (long)d * 512 + c, isbf);
        }
        acc += __shfl_xor(acc, 1); acc += __shfl_xor(acc, 2);
        if (cl == 0) av[d] = acc + inp(lb, d, isbf);
    }
    __syncthreads();
    L[tid + 512] = av[tid];
    L[tid + 768] = av[tid + 256];
    __syncthreads();
    // ---- word (softmax(qa)*qa folded) ----
    float m = fmaxf(fmaxf(L[tid], L[tid + 256]), fmaxf(L[tid + 512], L[tid + 768]));
    red[tid] = m; __syncthreads();
    for (int s = 128; s > 0; s >>= 1) { if (tid < s) red[tid] = fmaxf(red[tid], red[tid + s]); __syncthreads(); }
    float M = red[0]; __syncthreads();
    float z = expf(L[tid] - M) + expf(L[tid + 256] - M) + expf(L[tid + 512] - M) + expf(L[tid + 768] - M);
    red[tid] = z; __syncthreads();
    for (int s = 128; s > 0; s >>= 1) { if (tid < s) red[tid] += red[tid + s]; __syncthreads(); }
    float Z = red[0];
    __syncthreads();
    for (int j = tid; j < 512; j += 256) {
        float o1 = expf(L[j] - M) / Z * L[j];
        float o2 = expf(L[j + 512] - M) / Z * L[j + 512];
        word[b * 512 + j] = o1 + o2;
    }
    // ---- hid = relu(qa @ w1^T + b1) ----
    for (int ht = 0; ht < 4; ++ht) {
        int h = ht * 64 + (tid >> 2);
        float acc = 0.f;
        for (int k = 0; k < 256; ++k) {
            int c = cl + 4 * k;
            acc += L[c] * inp(w1, (long)h * 1024 + c, isbf);
        }
        acc += __shfl_xor(acc, 1); acc += __shfl_xor(acc, 2);
        if (cl == 0) {
            float v = acc + inp(b1, h, isbf);
            hidL[h] = v > 0.f ? v : 0.f;
        }
    }
    __syncthreads();
    // ---- gates + feat ----
    if (tid < 8) {
        float gl = inp(b2, tid, isbf);
        for (int j = 0; j < 256; ++j) gl += hidL[j] * inp(w2, tid * 256 + j, isbf);
        gates[tid] = gl;
    }
    {
        int f = tid >> 1, half = tid & 1;
        float acc = 0.f;
        for (int k = 0; k < 256; ++k) {
            int c = half + 2 * k;
            acc += av[c] * inp(lw2, (long)f * 512 + c, isbf);
        }
        acc += __shfl_xor(acc, 1);
        if (half == 0) feat[f] = acc + inp(lb2, f, isbf);
    }
    __syncthreads();
    if (tid == 0) {
        float mx = gates[0];
        for (int e = 1; e < 8; ++e) mx = fmaxf(mx, gates[e]);
        float zz = 0.f;
        for (int e = 0; e < 8; ++e) { gates[e] = expf(gates[e] - mx); zz += gates[e]; }
        for (int e = 0; e < 8; ++e) gates[e] /= zz;
    }
    __syncthreads();
    if (tid < 23) {
        float a = 0.f;
        for (int e = 0; e < 8; ++e) {
            float d = inp(ebias, e * 23 + tid, isbf);
            for (int ff = 0; ff < 128; ++ff) d += inp(ew, (e * 23 + tid) * 128 + ff, isbf) * feat[ff];
            a += gates[e] * d;
        }
        outw(out, OUT_LOGITS + b * 23 + tid, a, isbf);
    }
}

// ---- word2 ----
__global__ void k_txt(const float* __restrict__ word, const void* __restrict__ tw,
                      const void* __restrict__ tb, float* __restrict__ word2,
                      const void* __restrict__ img) {
    int isbf = detect_bf(img);
    int n = blockIdx.x, tid = threadIdx.x;
    __shared__ float wL[8][512];
    __shared__ float red[256 * 8];
    for (int e = tid; e < 4096; e += 256) wL[e >> 9][e & 511] = word[e];
    __syncthreads();
    float acc[8] = {0, 0, 0, 0, 0, 0, 0, 0};
    for (int c = tid; c < 512; c += 256) {
        float tv = inp(tw, (long)n * 512 + c, isbf);
        for (int b = 0; b < 8; ++b) acc[b] += wL[b][c] * tv;
    }
    for (int b = 0; b < 8; ++b) red[tid * 8 + b] = acc[b];
    __syncthreads();
    for (int s = 128; s > 0; s >>= 1) {
        if (tid < s) for (int b = 0; b < 8; ++b) red[tid * 8 + b] += red[(tid + s) * 8 + b];
        __syncthreads();
    }
    if (tid < 8) word2[tid * 2305 + n] = red[tid] + inp(tb, n, isbf);
}

// ---- eff_w / eff_b ----
__global__ void k_eff(const float* __restrict__ word2, const void* __restrict__ w3,
                      const void* __restrict__ b3, float* __restrict__ effw,
                      float* __restrict__ effb, const void* __restrict__ img) {
    int isbf = detect_bf(img);
    int bid = blockIdx.x;
    int b = bid / 9, tap = bid - b * 9;
    int tid = threadIdx.x;
    __shared__ float dw[256];
    dw[tid] = word2[b * 2305 + tid * 9 + tap];
    __syncthreads();
    float acc = 0.f;
    for (int c = 0; c < 256; ++c) acc += dw[c] * inp(w3, c * 256 + tid, isbf);
    effw[(b * 9 + tap) * 256 + tid] = acc;
    if (tid == 0) {
        float e = 0.f;
        for (int c = 0; c < 256; ++c) e += dw[c] * inp(b3, c, isbf);
        effb[b * 9 + tap] = e;
    }
}

// ---- epilogue helper for 32x32 C/D tiles: col=lane&31, row=(r&3)+8*(r>>2)+4*hi ----
__device__ __forceinline__ void epi32(const floatx16& Acc, int pxbase, int co4,
        int csh, int Cout, int tY, int tX, int b, int OW2, int hi,
        __hip_bfloat16* __restrict__ out, float& s1, float& s2) {
    int par = co4 >> csh; int co = co4 & (Cout - 1);
    int fyo = par >> 1, fxo = par & 1;
#pragma unroll
    for (int r = 0; r < 16; ++r) {
        int row = (r & 3) + 8 * (r >> 2) + 4 * hi;
        int px = pxbase + row;
        int fy = (((tY << 3) + (px >> 4)) << 1) + fyo;
        int fx = (((tX << 4) + (px & 15)) << 1) + fxo;
        float v = Acc[r];
        out[(((long)(b * OW2 + fy)) * OW2 + fx) * Cout + co] = F2BF(v);
        s1 += v; s2 += v * v;
    }
}

// ---- k_conv4 v7 (round-8 verified): weights loaded ONCE per block ----
__global__ __launch_bounds__(256, 3) void k_conv4(const __hip_bfloat16* __restrict__ in,
        const __hip_bfloat16* __restrict__ w4, __hip_bfloat16* __restrict__ out,
        int inH, int inW, int Cout, float* __restrict__ s1o, float* __restrict__ s2o,
        const float* __restrict__ bnS1, const float* __restrict__ bnS2,
        const void* __restrict__ g, const void* __restrict__ bb, float invN,
        const void* __restrict__ img) {
    int Cout4 = Cout << 2;
    int csh = (Cout == 512) ? 9 : 8;
    int G = Cout4 >> 5;
    int tXn = inW >> 4, tYn = inH >> 3;
    int bid = blockIdx.y;
    int tX = bid % tXn; int tmp = bid / tXn; int tY = tmp % tYn; int b = tmp / tYn;
    int co0 = blockIdx.x * 128;
    __shared__ __align__(16) __hip_bfloat16 Hs[4 * 1448];
    __shared__ float scT[512], shT[512];
    int tid = threadIdx.x;
    int l = tid & 63, l31 = l & 31, hi = l >> 5;
    int wave = tid >> 6;
    int dobn = (bnS1 != nullptr);
    if (dobn) {
        int isbf = detect_bf(img);
        for (int c = tid; c < 512; c += 256) {
            float m = bnS1[c] * invN, var = bnS2[c] * invN - m * m;
            float sc = inp(g, c, isbf) * rsqrtf(var + 1e-5f);
            scT[c] = sc; shT[c] = inp(bb, c, isbf) - m * sc;
        }
    }
    int R0 = (tY << 3) - 1, C0 = (tX << 4) - 1;
    long base = (long)b * inH * inW;
    int sub = tid & 3;
    const __hip_bfloat16* ga[3];
    int wo[3];
#pragma unroll
    for (int s = 0; s < 3; ++s) {
        int gi = tid + s * 256;
        int p = gi >> 2; if (p > 179) p = 179;
        int hy = p / 18, hx = p - hy * 18;
        int gr = R0 + hy; gr = gr < 0 ? 0 : (gr > inH - 1 ? inH - 1 : gr);
        int gc = C0 + hx; gc = gc < 0 ? 0 : (gc > inW - 1 ? inW - 1 : gc);
        ga[s] = in + (base + (long)gr * inW + gc) * 512 + sub * 8;
        wo[s] = sub * 1448 + p * 8;
    }
    int has2 = (tid < 208);
    short8 r0 = *(const short8*)(ga[0]);
    short8 r1 = *(const short8*)(ga[1]);
    short8 r2 = {0, 0, 0, 0, 0, 0, 0, 0};
    if (has2) r2 = *(const short8*)(ga[2]);
    int qA = hi * 1448;
    int qB = qA + 2896;
    int h[4];
#pragma unroll
    for (int i = 0; i < 4; ++i) {
        int px = i * 32 + l31;
        h[i] = ((px >> 4) * 18 + (px & 15)) * 8;
    }
    const __hip_bfloat16* wl2 = w4 + (long)l * 8;
    int cgw = (co0 >> 5) + wave;
    short8 wS0[2], wS1[2], wS2[2];
#define LDW(S, t, c) { long fb = (((long)((t) * 16 + (c)) * G + cgw) * 2) * 512; \
    S[0] = *(const short8*)(wl2 + fb); \
    S[1] = *(const short8*)(wl2 + fb + 512); }
    floatx16 zero16 = {0,0,0,0,0,0,0,0,0,0,0,0,0,0,0,0};
    floatx16 a[4];
#pragma unroll
    for (int i = 0; i < 4; ++i) a[i] = zero16;
    LDW(wS0, 0, 0);
    for (int ci0 = 0; ci0 < 512; ci0 += 32) {
        int cc = ci0 >> 5;
        __syncthreads();
        if (dobn) {
            float scv[8], shv[8];
#pragma unroll
            for (int k = 0; k < 8; ++k) { int c = ci0 + sub * 8 + k; scv[k] = scT[c]; shv[k] = shT[c]; }
#pragma unroll
            for (int k = 0; k < 8; ++k) {
                float f0 = bfbits2f(r0[k]) * scv[k] + shv[k]; r0[k] = f2bfbits(f0 > 0.f ? f0 : 0.f);
                float f1 = bfbits2f(r1[k]) * scv[k] + shv[k]; r1[k] = f2bfbits(f1 > 0.f ? f1 : 0.f);
                float f2 = bfbits2f(r2[k]) * scv[k] + shv[k]; r2[k] = f2bfbits(f2 > 0.f ? f2 : 0.f);
            }
        }
        *(short8*)(Hs + wo[0]) = r0;
        *(short8*)(Hs + wo[1]) = r1;
        if (has2) *(short8*)(Hs + wo[2]) = r2;
        __syncthreads();
        if (ci0 < 480) {
            r0 = *(const short8*)(ga[0] + ci0 + 32);
            r1 = *(const short8*)(ga[1] + ci0 + 32);
            if (has2) r2 = *(const short8*)(ga[2] + ci0 + 32);
        }
#pragma unroll
        for (int tap = 0; tap < 9; ++tap) {
            {
                int nt = tap + 1, ncc = cc;
                if (nt == 9) { nt = 0; ncc = cc + 1; }
                if (ncc < 16) {
                    if (((tap + 1) % 3) == 0)      { LDW(wS0, nt, ncc); }
                    else if (((tap + 1) % 3) == 1) { LDW(wS1, nt, ncc); }
                    else                            { LDW(wS2, nt, ncc); }
                }
            }
            int dy = tap / 3, dx = tap - dy * 3;
            int hoE = (dy * 18 + dx) * 8;
            if ((tap % 3) == 0) {
#pragma unroll
                for (int i = 0; i < 4; ++i) {
                    short8 af0 = *(const short8*)(Hs + qA + h[i] + hoE);
                    short8 af1 = *(const short8*)(Hs + qB + h[i] + hoE);
                    a[i] = __builtin_amdgcn_mfma_f32_32x32x16_bf16(af0, wS0[0], a[i], 0, 0, 0);
                    a[i] = __builtin_amdgcn_mfma_f32_32x32x16_bf16(af1, wS0[1], a[i], 0, 0, 0);
                }
            } else if ((tap % 3) == 1) {
#pragma unroll
                for (int i = 0; i < 4; ++i) {
                    short8 af0 = *(const short8*)(Hs + qA + h[i] + hoE);
                    short8 af1 = *(const short8*)(Hs + qB + h[i] + hoE);
                    a[i] = __builtin_amdgcn_mfma_f32_32x32x16_bf16(af0, wS1[0], a[i], 0, 0, 0);
                    a[i] = __builtin_amdgcn_mfma_f32_32x32x16_bf16(af1, wS1[1], a[i], 0, 0, 0);
                }
            } else {
#pragma unroll
                for (int i = 0; i < 4; ++i) {
                    short8 af0 = *(const short8*)(Hs + qA + h[i] + hoE);
                    short8 af1 = *(const short8*)(Hs + qB + h[i] + hoE);
                    a[i] = __builtin_amdgcn_mfma_f32_32x32x16_bf16(af0, wS2[0], a[i], 0, 0, 0);
                    a[i] = __builtin_amdgcn_mfma_f32_32x32x16_bf16(af1, wS2[1], a[i], 0, 0, 0);
                }
            }
        }
    }
#undef LDW
    int OW2 = inW << 1;
    float s1v = 0.f, s2v = 0.f;
    int co4w = co0 + wave * 32 + l31;
#pragma unroll
    for (int i = 0; i < 4; ++i)
        epi32(a[i], i * 32, co4w, csh, Cout, tY, tX, b, OW2, hi, out, s1v, s2v);
    s1v += __shfl_xor(s1v, 32); s2v += __shfl_xor(s2v, 32);
    if (hi == 0) {
        int ch = co4w & (Cout - 1);
        atomicAdd(s1o + ch, s1v);
        atomicAdd(s2o + ch, s2v);
    }
}

// ---- k_efix: boundary repair (16x16 MFMA path, unchanged semantics) ----
__global__ __launch_bounds__(256) void k_efix(const __hip_bfloat16* __restrict__ in,
        __hip_bfloat16* __restrict__ Y, const __hip_bfloat16* __restrict__ wRo,
        int inW, int Cout, int ebase,
        float* __restrict__ s1o, float* __restrict__ s2o) {
    int OW = inW << 1;
    int coT = Cout >> 6;
    int b = blockIdx.x / coT, cot = blockIdx.x - b * coT;
    int co0 = cot << 6;
    int e = ebase + blockIdx.y;   // 0 top, 1 bottom, 2 left, 3 right
    __shared__ __align__(16) __hip_bfloat16 E[130 * 40];
    __shared__ __align__(16) __hip_bfloat16 Lline[64 * 32];
    int tid = threadIdx.x;
    int wave = tid >> 6, l = tid & 63, lm = l & 15, q = l >> 4;
    int mspan = OW >> 2;
    int ilim = OW >> 6;
    int mb = wave * mspan;
    floatx4 zero4 = {0.f, 0.f, 0.f, 0.f};
    floatx4 acc[2][4];
    for (int i = 0; i < 2; ++i) for (int j = 0; j < 4; ++j) acc[i][j] = zero4;
    int lineG = inW * 4;
    int eG = (OW + 2) * 4;
    int haveL = (tid < lineG);
    const __hip_bfloat16* lbase = in;
    {
        int x = tid >> 2, sb = tid & 3;
        long gidx;
        if (e < 2) { int R = (e == 0) ? 0 : inW - 1; gidx = (long)(b * inW + R) * inW + x; }
        else       { int Cc = (e == 2) ? 0 : inW - 1; gidx = (long)(b * inW + x) * inW + Cc; }
        if (x >= inW) gidx = (long)b * inW * inW;
        lbase = in + gidx * 512 + sb * 8;
    }
    short8 rl = {0, 0, 0, 0, 0, 0, 0, 0};
    if (haveL) rl = *(const short8*)(lbase);
    for (int ci0 = 0; ci0 < 512; ci0 += 32) {
        __syncthreads();
        if (haveL) *(short8*)(Lline + tid * 8) = rl;
        __syncthreads();
        if (ci0 < 480 && haveL) rl = *(const short8*)(lbase + ci0 + 32);
        for (int t = tid; t < eG; t += 256) {
            int f1 = t >> 2, sb = t & 3;
            int f = f1 - 1;
            short8 res = {0, 0, 0, 0, 0, 0, 0, 0};
            if (f < 0 || f >= OW) {
                if (e < 2) { int xx = (f < 0) ? 0 : inW - 1; res = *(const short8*)(Lline + (xx * 4 + sb) * 8); }
            } else {
                int x0; float w0;
                if (f & 1) { x0 = f >> 1; w0 = 0.75f; } else { x0 = (f >> 1) - 1; w0 = 0.25f; }
                int x1 = x0 + 1;
                if (x0 < 0) x0 = 0;
                if (x1 > inW - 1) x1 = inW - 1;
                short8 v0 = *(const short8*)(Lline + (x0 * 4 + sb) * 8);
                short8 v1 = *(const short8*)(Lline + (x1 * 4 + sb) * 8);
                float w1c = 1.f - w0;
#pragma unroll
                for (int k = 0; k < 8; ++k)
                    res[k] = f2bfbits(w0 * bfbits2f(v0[k]) + w1c * bfbits2f(v1[k]));
            }
            *(short8*)(E + f1 * 40 + sb * 8) = res;
        }
        __syncthreads();
        int cc = ci0 >> 5;
#pragma unroll
        for (int t = 0; t < 3; ++t) {
            int tap = (e == 0) ? t : (e == 1) ? (6 + t) : (e == 2) ? (t * 3) : (t * 3 + 2);
            short8 bfv[4];
#pragma unroll
            for (int j = 0; j < 4; ++j)
                bfv[j] = *(const short8*)(wRo + ((long)(tap * 16 + cc) * Cout + co0 + j * 16 + lm) * 32 + q * 8);
#pragma unroll
            for (int i = 0; i < 2; ++i) {
                if (i < ilim) {
                    short8 af = *(const short8*)(E + (mb + i * 16 + lm + t) * 40 + q * 8);
#pragma unroll
                    for (int j = 0; j < 4; ++j)
                        acc[i][j] = __builtin_amdgcn_mfma_f32_16x16x32_bf16(af, bfv[j], acc[i][j], 0, 0, 0);
                }
            }
        }
    }
    float d1s[4] = {0.f, 0.f, 0.f, 0.f}, d2s[4] = {0.f, 0.f, 0.f, 0.f};
    for (int i = 0; i < ilim; ++i)
#pragma unroll
    for (int j = 0; j < 4; ++j) {
        int co = co0 + j * 16 + lm;
#pragma unroll
        for (int r = 0; r < 4; ++r) {
            int m = mb + i * 16 + q * 4 + r;
            int fy, fx;
            if (e == 0) { fy = 0; fx = m; }
            else if (e == 1) { fy = OW - 1; fx = m; }
            else if (e == 2) { fy = m; fx = 0; }
            else { fy = m; fx = OW - 1; }
            long a = (((long)(b * OW + fy)) * OW + fx) * Cout + co;
            float vo = BF2F(Y[a]);
            float vn = vo - acc[i][j][r];
            Y[a] = F2BF(vn);
            d1s[j] += vn - vo;
            d2s[j] += vn * vn - vo * vo;
        }
    }
#pragma unroll
    for (int j = 0; j < 4; ++j) {
        d1s[j] += __shfl_xor(d1s[j], 16); d1s[j] += __shfl_xor(d1s[j], 32);
        d2s[j] += __shfl_xor(d2s[j], 16); d2s[j] += __shfl_xor(d2s[j], 32);
    }
    if (q == 0) {
#pragma unroll
        for (int j = 0; j < 4; ++j) {
            atomicAdd(s1o + co0 + j * 16 + lm, d1s[j]);
            atomicAdd(s2o + co0 + j * 16 + lm, d2s[j]);
        }
    }
}

// ---- masks ----
__global__ __launch_bounds__(256) void k_masks(const __hip_bfloat16* __restrict__ x2,
                                               const float* __restrict__ effw,
                                               const float* __restrict__ effb,
                                               const float* __restrict__ word2,
                                               void* __restrict__ mout,
                                               const float* __restrict__ s1,
                                               const float* __restrict__ s2,
                                               const void* __restrict__ g,
                                               const void* __restrict__ bb, float invN,
                                               const void* __restrict__ img) {
    int isbf = detect_bf(img);
    int bid = blockIdx.x;
    int tX = bid & 15, tY = (bid >> 4) & 15, b = bid >> 8;
    __shared__ __align__(16) __hip_bfloat16 H[100 * 264];
    __shared__ __align__(16) float EW[9 * 256];
    __shared__ float EB[9];
    __shared__ float sc2T[256];
    __shared__ float sh2T[256];
    int tid = threadIdx.x;
    {
        float m = s1[tid] * invN, var = s2[tid] * invN - m * m;
        float sc = inp(g, tid, isbf) * rsqrtf(var + 1e-5f);
        sc2T[tid] = sc; sh2T[tid] = inp(bb, tid, isbf) - m * sc;
    }
    __syncthreads();
    for (int e = tid; e < 3200; e += 256) {
        int c8 = e & 31, p = e >> 5;
        int hy = p / 10, hx = p - hy * 10;
        int gy = tY * 8 + hy - 1, gx = tX * 8 + hx - 1;
        short8 res = {0, 0, 0, 0, 0, 0, 0, 0};
        if (gy >= 0 && gy < 128 && gx >= 0 && gx < 128) {
            short8 raw = *(const short8*)(x2 + (((long)(b * 128 + gy)) * 128 + gx) * 256 + c8 * 8);
#pragma unroll
            for (int k = 0; k < 8; ++k) {
                int c = c8 * 8 + k;
                float v = bfbits2f(raw[k]) * sc2T[c] + sh2T[c];
                res[k] = f2bfbits(v > 0.f ? v : 0.f);
            }
        }
        *(short8*)(H + p * 264 + c8 * 8) = res;
    }
    for (int e = tid; e < 2304; e += 256) EW[e] = effw[b * 2304 + e];
    if (tid < 9) EB[tid] = effb[b * 9 + tid];
    __syncthreads();
    int px = tid & 63, part = tid >> 6;
    int py = px >> 3, pxc = px & 7;
    int cbase = part * 64;
    float acc = 0.f;
    for (int tap = 0; tap < 9; ++tap) {
        int ky = tap / 3, kx = tap - ky * 3;
        int hp = (py + ky) * 10 + pxc + kx;
        const __hip_bfloat16* hrow = H + (long)hp * 264 + cbase;
        const float* erow = EW + tap * 256 + cbase;
#pragma unroll
        for (int c8 = 0; c8 < 8; ++c8) {
            short8 h8 = *(const short8*)(hrow + c8 * 8);
            floatx4 e0 = *(const floatx4*)(erow + c8 * 8);
            floatx4 e1 = *(const floatx4*)(erow + c8 * 8 + 4);
            acc += bfbits2f(h8[0]) * e0[0] + bfbits2f(h8[1]) * e0[1] +
                   bfbits2f(h8[2]) * e0[2] + bfbits2f(h8[3]) * e0[3] +
                   bfbits2f(h8[4]) * e1[0] + bfbits2f(h8[5]) * e1[1] +
                   bfbits2f(h8[6]) * e1[2] + bfbits2f(h8[7]) * e1[3];
        }
    }
    float (*red)[64] = (float(*)[64])sc2T;
    red[part][px] = acc;
    __syncthreads();
    if (part == 0) {
        float s = red[0][px] + red[1][px] + red[2][px] + red[3][px];
        int oy = tY * 8 + py, ox = tX * 8 + pxc;
        float bias = word2[b * 2305 + 2304];
        for (int tap = 0; tap < 9; ++tap) {
            int ky = tap / 3, kx = tap - ky * 3;
            int iy = oy + ky - 1, ix = ox + kx - 1;
            if (iy >= 0 && iy < 128 && ix >= 0 && ix < 128) bias += EB[tap];
        }
        outw(mout, b * 16384 + oy * 128 + ox, s + bias, isbf);
    }
}

extern "C" void kernel_launch(void* const* d_in, const int* in_sizes, int n_in,
                              void* d_out, int out_size, void* d_ws, size_t ws_size,
                              hipStream_t stream) {
    (void)in_sizes; (void)n_in; (void)out_size; (void)ws_size;
    const void* img   = d_in[0];
    const void* state = d_in[2];
    const void* Wt    = d_in[4];
    const void* cw1   = d_in[7];
    const void* g1    = d_in[8];
    const void* bb1   = d_in[9];
    const void* cw2   = d_in[10];
    const void* g2    = d_in[11];
    const void* bb2   = d_in[12];
    const void* w3    = d_in[13];
    const void* b3    = d_in[14];
    const void* txtw  = d_in[15];
    const void* txtb  = d_in[16];
    const void* lnw   = d_in[17];
    const void* lnb   = d_in[18];
    const void* lnw2  = d_in[19];
    const void* lnb2  = d_in[20];
    const void* rw1   = d_in[21];
    const void* rb1   = d_in[22];
    const void* rw2   = d_in[23];
    const void* rb2   = d_in[24];
    const void* ew    = d_in[25];
    const void* eb    = d_in[26];

    char* ws = (char*)d_ws;
    __hip_bfloat16* W4R2 = (__hip_bfloat16*)(ws + WS_W4R2);
    __hip_bfloat16* WRO2 = (__hip_bfloat16*)(ws + WS_WRO2);
    __hip_bfloat16* WRO1 = (__hip_bfloat16*)(ws + WS_WRO1);
    __hip_bfloat16* Y1   = (__hip_bfloat16*)(ws + WS_Y1);
    __hip_bfloat16* Y2   = (__hip_bfloat16*)(ws + WS_Y2);
    __hip_bfloat16* W4R1 = (__hip_bfloat16*)(ws + WS_W4R1);
    __hip_bfloat16* A    = (__hip_bfloat16*)(ws + WS_A);
    __hip_bfloat16* WTB  = (__hip_bfloat16*)(ws + WS_WTB);
    __hip_bfloat16* SRCB = (__hip_bfloat16*)(ws + WS_SRCB);
    float* S1A = (float*)(ws + WS_STATS);
    float* S2A = S1A + 512;
    float* S1B = S1A + 1024;
    float* S2B = S1A + 1536;
    float* ANS   = (float*)(ws + WS_ANS);
    float* WORD  = (float*)(ws + WS_WORD);
    float* WORD2 = (float*)(ws + WS_WORD2);
    float* EFFW  = (float*)(ws + WS_EFFW);
    float* EFFB  = (float*)(ws + WS_EFFB);

    k_pre<<<5889, 256, 0, stream>>>(img, cw1, cw2, Wt, A, W4R1, W4R2, WRO1, WRO2, WTB,
                                    (float*)(ws + WS_STATS));
    k_gemm1<<<dim3(64, 4), 256, 0, stream>>>(A, WTB, SRCB, d_out, ANS, img);
    k_head<<<8, 256, 0, stream>>>(ANS, lnw, lnb, state, WORD, rw1, rb1, rw2, rb2,
                                  lnw2, lnb2, ew, eb, d_out, img);
    k_txt<<<2305, 256, 0, stream>>>(WORD, txtw, txtb, WORD2, img);
    k_eff<<<72, 256, 0, stream>>>(WORD2, w3, b3, EFFW, EFFB, img);
    // conv1: composed at orig res 32x32 (128px x 128co4 blocks), Cout4=2048
    k_conv4<<<dim3(16, 64), 256, 0, stream>>>(SRCB, W4R1, Y1, 32, 32, 512, S1A, S2A,
                                              nullptr, nullptr, nullptr, nullptr, 0.f, img);
    k_efix<<<dim3(64, 2), 256, 0, stream>>>(SRCB, Y1, WRO1, 32, 512, 0, S1A, S2A);
    k_efix<<<dim3(64, 2), 256, 0, stream>>>(SRCB, Y1, WRO1, 32, 512, 2, S1A, S2A);
    // conv2: composed at orig res 64x64, Cout4=1024, bn1+relu fused into halo staging
    k_conv4<<<dim3(8, 256), 256, 0, stream>>>(Y1, W4R2, Y2, 64, 64, 256, S1B, S2B,
                                              S1A, S2A, g1, bb1, 1.f / 32768.f, img);
    k_efix<<<dim3(32, 2), 256, 0, stream>>>(Y1, Y2, WRO2, 64, 256, 0, S1B, S2B);
    k_efix<<<dim3(32, 2), 256, 0, stream>>>(Y1, Y2, WRO2, 64, 256, 2, S1B, S2B);
    k_masks<<<2048, 256, 0, stream>>>(Y2, EFFW, EFFB, WORD2, d_out,
                                      S1B, S2B, g2, bb2, 1.f / 131072.f, img);
}

// Round 10
// 1014.829 us; speedup vs baseline: 1.1576x; 1.1576x over previous
//
#include <hip/hip_runtime.h>
#include <hip/hip_bf16.h>

typedef __attribute__((ext_vector_type(8))) short short8;
typedef __attribute__((ext_vector_type(4))) short shortx4;
typedef __attribute__((ext_vector_type(4))) float floatx4;
typedef __attribute__((ext_vector_type(16))) float floatx16;

#define F2BF __float2bfloat16
#define BF2F __bfloat162float

// ---------------- workspace layout (byte offsets), total ~112.0 MiB ----------------
#define WS_W4R2   0UL
#define WS_WRO2   9437184UL
#define WS_WRO1   11796480UL
#define WS_Y1     16515072UL
#define WS_Y2     50069504UL
#define WS_W4R1   50069504UL
#define WS_A      68943872UL
#define WS_WTB    77332480UL
#define WS_SRCB   77856768UL
#define WS_STATS  117178368UL
#define WS_ANS    117186560UL
#define WS_QA     117207040UL
#define WS_ANSV   117239808UL
#define WS_WORD   117256192UL
#define WS_WORD2  117272576UL
#define WS_EFFW   117346336UL
#define WS_EFFB   117420064UL
#define WS_HID    117420352UL

#define OUT_LOGITS 131072
#define OUT_SRC    131256

__device__ __forceinline__ float inp(const void* p, long i, int isbf) {
    return isbf ? BF2F(((const __hip_bfloat16*)p)[i]) : ((const float*)p)[i];
}
__device__ __forceinline__ void outw(void* p, long i, float v, int isbf) {
    if (isbf) ((__hip_bfloat16*)p)[i] = F2BF(v);
    else      ((float*)p)[i] = v;
}
__device__ __forceinline__ float bfbits2f(short s) {
    unsigned int u = ((unsigned int)(unsigned short)s) << 16;
    float f; __builtin_memcpy(&f, &u, 4); return f;
}
__device__ __forceinline__ short f2bfbits(float f) {
    __hip_bfloat16 h = F2BF(f);
    short s; __builtin_memcpy(&s, &h, 2); return s;
}

__device__ __forceinline__ int detect_bf(const void* img) {
    const unsigned short* u = (const unsigned short*)img;
    int l = threadIdx.x & 63;
    int c = 0;
#pragma unroll
    for (int k = 0; k < 8; ++k) {
        int e = (u[(l * 8 + k) * 2] >> 7) & 0xFF;
        c += (e >= 100 && e <= 150) ? 1 : 0;
    }
    for (int off = 32; off; off >>= 1) c += __shfl_xor(c, off, 64);
    return c > 307;
}

__device__ __forceinline__ float pe_val(int n, int c) {
    float pos = (c < 256) ? (float)(n & 31) : (float)(n >> 5);
    int i = ((c < 256) ? c : (c - 256)) >> 1;
    float ang = pos * expf(-0.0719557841560639f * (float)i);
    return (c & 1) ? cosf(ang) : sinf(ang);
}

// ---- fused prep (+ stats zeroing block) ----
// W4 layout (fragment-contiguous): [tap][cc(16)][cog(Cout4/32)][ksub(2)][lane(64)][8ci]
__global__ void k_pre(const void* __restrict__ img, const void* __restrict__ cw1,
                      const void* __restrict__ cw2, const void* __restrict__ Wt,
                      __hip_bfloat16* __restrict__ A,
                      __hip_bfloat16* __restrict__ W4R1, __hip_bfloat16* __restrict__ W4R2,
                      __hip_bfloat16* __restrict__ WRo1, __hip_bfloat16* __restrict__ WRo2,
                      __hip_bfloat16* __restrict__ WTB, float* __restrict__ STZ) {
    int isbf = detect_bf(img);
    int bid = blockIdx.x, tid = threadIdx.x;
    __shared__ float LS[2304];
    if (bid < 4096) {
        int nt = bid & 31, ct = (bid >> 5) & 15, b = bid >> 9;
        int tx = tid & 31, ty = tid >> 5;
        int c0 = ct * 32, n0 = nt * 32;
        for (int j = 0; j < 4; ++j) {
            int c = c0 + ty + j * 8;
            LS[(ty + j * 8) * 33 + tx] = inp(img, ((long)(b * 512 + c)) * 1024 + n0 + tx, isbf);
        }
        __syncthreads();
        for (int j = 0; j < 4; ++j) {
            int n = n0 + ty + j * 8, c = c0 + tx;
            A[((long)(b * 1024 + n)) * 512 + c] = F2BF(LS[tx * 33 + ty + j * 8] + pe_val(n, c));
        }
    } else if (bid < 5632) {
        int bb = bid - 4096;
        const void* w; __hip_bfloat16 *w4, *wo; int Cout, r0;
        if (bb < 1024) { w = cw1; w4 = W4R1; wo = WRo1; Cout = 512; r0 = bb * 256; }
        else           { w = cw2; w4 = W4R2; wo = WRo2; Cout = 256; r0 = (bb - 1024) * 256; }
        int Cout4 = Cout << 2;
        int G = Cout4 >> 5;
        int co = r0 >> 9, ci0 = r0 & 511;
        for (int e = tid; e < 2304; e += 256) LS[e] = inp(w, (long)r0 * 9 + e, isbf);
        __syncthreads();
        int ci = ci0 + tid;
        int cc = ci >> 5, cw = ci & 31;
        int ksub = (ci >> 4) & 1, hic = (ci >> 3) & 1, ee = ci & 7;
        float w9[9];
#pragma unroll
        for (int t = 0; t < 9; ++t) w9[t] = LS[tid * 9 + t];
#pragma unroll
        for (int t = 0; t < 9; ++t)
            wo[((long)(t * 16 + cc) * Cout + co) * 32 + cw] = F2BF(w9[t]);
        const float BY[2][3][3] = {{{0.75f, 0.25f, 0.f}, {0.25f, 0.75f, 0.75f}, {0.f, 0.f, 0.25f}},
                                   {{0.25f, 0.f, 0.f},  {0.75f, 0.75f, 0.25f}, {0.f, 0.25f, 0.75f}}};
#pragma unroll
        for (int p = 0; p < 4; ++p) {
            int py = p >> 1, px = p & 1;
            int co4 = p * Cout + co;
            int cog = co4 >> 5, l31c = co4 & 31;
#pragma unroll
            for (int dy = 0; dy < 3; ++dy)
#pragma unroll
            for (int dx = 0; dx < 3; ++dx) {
                float v = 0.f;
#pragma unroll
                for (int ky = 0; ky < 3; ++ky)
#pragma unroll
                for (int kx = 0; kx < 3; ++kx)
                    v += BY[py][dy][ky] * BY[px][dx][kx] * w9[ky * 3 + kx];
                long fi = ((((long)((dy * 3 + dx) * 16 + cc) * G + cog) * 2 + ksub) * 64
                           + hic * 32 + l31c) * 8 + ee;
                w4[fi] = F2BF(v);
            }
        }
    } else if (bid < 5888) {
        for (int i = (bid - 5632) * 256 + tid; i < 512 * 512; i += 256 * 256)
            WTB[i] = F2BF(inp(Wt, i, isbf));
    } else {
        for (int i = tid; i < 6144; i += 256) STZ[i] = 0.f;   // stats + ANS zero
    }
}

// ---- MFMA GEMM + fused epilogue (reg-prefetch staging) ----
__global__ __launch_bounds__(256) void k_gemm1(const __hip_bfloat16* __restrict__ A,
                                               const __hip_bfloat16* __restrict__ Bw,
                                               __hip_bfloat16* __restrict__ srcB,
                                               void* __restrict__ dst,
                                               float* __restrict__ ANS,
                                               const void* __restrict__ img) {
    int isbf = detect_bf(img);
    __shared__ __align__(16) __hip_bfloat16 As[128 * 32];
    __shared__ __align__(16) __hip_bfloat16 Bs[128 * 32];
    int m0 = blockIdx.x * 128, n0 = blockIdx.y * 128;
    int tid = threadIdx.x;
    int wave = tid >> 6, l = tid & 63, lm = l & 15, q = l >> 4;
    int wm = wave & 1, wn = wave >> 1;
    int m_0 = tid >> 2, qq0 = tid & 3;
    int m_1 = (tid + 256) >> 2, qq1 = qq0;
    const __hip_bfloat16* aA0 = A + ((long)(m0 + m_0)) * 512 + qq0 * 8;
    const __hip_bfloat16* aB0 = Bw + ((long)(n0 + m_0)) * 512 + qq0 * 8;
    const __hip_bfloat16* aA1 = A + ((long)(m0 + m_1)) * 512 + qq1 * 8;
    const __hip_bfloat16* aB1 = Bw + ((long)(n0 + m_1)) * 512 + qq1 * 8;
    int wA0 = m_0 * 32 + qq0 * 8, wA1 = m_1 * 32 + qq1 * 8;
    short8 rA0 = *(const short8*)(aA0), rB0 = *(const short8*)(aB0);
    short8 rA1 = *(const short8*)(aA1), rB1 = *(const short8*)(aB1);
    floatx4 zero4 = {0.f, 0.f, 0.f, 0.f};
    floatx4 acc[4][4];
    for (int i = 0; i < 4; ++i) for (int j = 0; j < 4; ++j) acc[i][j] = zero4;
    for (int k0 = 0; k0 < 512; k0 += 32) {
        __syncthreads();
        *(short8*)(As + wA0) = rA0; *(short8*)(Bs + wA0) = rB0;
        *(short8*)(As + wA1) = rA1; *(short8*)(Bs + wA1) = rB1;
        __syncthreads();
        if (k0 < 480) {
            rA0 = *(const short8*)(aA0 + k0 + 32); rB0 = *(const short8*)(aB0 + k0 + 32);
            rA1 = *(const short8*)(aA1 + k0 + 32); rB1 = *(const short8*)(aB1 + k0 + 32);
        }
        short8 af[4], bfv[4];
#pragma unroll
        for (int t = 0; t < 4; ++t) af[t] = *(short8*)(As + (wm * 64 + t * 16 + lm) * 32 + q * 8);
#pragma unroll
        for (int t = 0; t < 4; ++t) bfv[t] = *(short8*)(Bs + (wn * 64 + t * 16 + lm) * 32 + q * 8);
#pragma unroll
        for (int i = 0; i < 4; ++i)
#pragma unroll
            for (int j = 0; j < 4; ++j)
                acc[i][j] = __builtin_amdgcn_mfma_f32_16x16x32_bf16(af[i], bfv[j], acc[i][j], 0, 0, 0);
    }
    int b = m0 >> 10, hw0 = m0 & 1023;
    float cs[4] = {0.f, 0.f, 0.f, 0.f};
#pragma unroll
    for (int i = 0; i < 4; ++i)
#pragma unroll
        for (int j = 0; j < 4; ++j) {
            int mrow = wm * 64 + i * 16 + q * 4;
            int n = n0 + wn * 64 + j * 16 + lm;
            long mg = (long)(m0 + mrow);
#pragma unroll
            for (int r = 0; r < 4; ++r) {
                float v = acc[i][j][r];
                srcB[(mg + r) * 512 + n] = F2BF(v);
                cs[j] += v;
            }
            long obase = (long)OUT_SRC + ((long)(b * 512 + n)) * 1024 + hw0 + mrow;
            if (isbf) {
                shortx4 pk = { f2bfbits(acc[i][j][0]), f2bfbits(acc[i][j][1]),
                               f2bfbits(acc[i][j][2]), f2bfbits(acc[i][j][3]) };
                *(shortx4*)((__hip_bfloat16*)dst + obase) = pk;
            } else {
                floatx4 pk = { acc[i][j][0], acc[i][j][1], acc[i][j][2], acc[i][j][3] };
                *(floatx4*)((float*)dst + obase) = pk;
            }
        }
#pragma unroll
    for (int j = 0; j < 4; ++j) {
        cs[j] += __shfl_xor(cs[j], 16);
        cs[j] += __shfl_xor(cs[j], 32);
    }
    __syncthreads();
    float* CS = (float*)Bs;
    if (wm == 1 && q == 0) {
#pragma unroll
        for (int j = 0; j < 4; ++j) CS[wn * 64 + j * 16 + lm] = cs[j];
    }
    __syncthreads();
    if (wm == 0 && q == 0) {
#pragma unroll
        for (int j = 0; j < 4; ++j) {
            int n = n0 + wn * 64 + j * 16 + lm;
            atomicAdd(ANS + b * 512 + n, cs[j] + CS[wn * 64 + j * 16 + lm]);
        }
    }
}

// ---- ansv ----
__global__ void k_ansvec(const float* __restrict__ ANS, const void* __restrict__ lw,
                         const void* __restrict__ lb, float* __restrict__ ansv,
                         const void* __restrict__ img) {
    int isbf = detect_bf(img);
    int b = blockIdx.x, dt = blockIdx.y, tid = threadIdx.x;
    __shared__ float aL[512];
    __shared__ float R[256];
    aL[tid] = ANS[b * 512 + tid] * (1.f / 1024.f);
    aL[tid + 256] = ANS[b * 512 + tid + 256] * (1.f / 1024.f);
    __syncthreads();
    int d = dt * 64 + (tid >> 2), cl = tid & 3;
    float acc = 0.f;
#pragma unroll 4
    for (int k = 0; k < 128; ++k) {
        int c = cl + 4 * k;
        acc += aL[c] * inp(lw, (long)d * 512 + c, isbf);
    }
    R[tid] = acc;
    __syncthreads();
    if (cl == 0)
        ansv[b * 512 + d] = R[tid] + R[tid + 1] + R[tid + 2] + R[tid + 3] + inp(lb, d, isbf);
}

// ---- word/qa ----
__global__ void k_word(const float* __restrict__ ansv, const void* __restrict__ state,
                       float* __restrict__ qa, float* __restrict__ word,
                       const void* __restrict__ img) {
    int isbf = detect_bf(img);
    int b = blockIdx.x, tid = threadIdx.x;
    __shared__ float L[1024];
    __shared__ float red[256];
    L[tid] = inp(state, b * 512 + tid, isbf);
    L[tid + 256] = inp(state, b * 512 + tid + 256, isbf);
    L[tid + 512] = ansv[b * 512 + tid];
    L[tid + 768] = ansv[b * 512 + tid + 256];
    __syncthreads();
    for (int j = tid; j < 1024; j += 256) qa[b * 1024 + j] = L[j];
    float m = fmaxf(fmaxf(L[tid], L[tid + 256]), fmaxf(L[tid + 512], L[tid + 768]));
    red[tid] = m; __syncthreads();
    for (int s = 128; s > 0; s >>= 1) { if (tid < s) red[tid] = fmaxf(red[tid], red[tid + s]); __syncthreads(); }
    float M = red[0]; __syncthreads();
    float z = expf(L[tid] - M) + expf(L[tid + 256] - M) + expf(L[tid + 512] - M) + expf(L[tid + 768] - M);
    red[tid] = z; __syncthreads();
    for (int s = 128; s > 0; s >>= 1) { if (tid < s) red[tid] += red[tid + s]; __syncthreads(); }
    float Z = red[0];
    for (int j = tid; j < 512; j += 256) {
        float o1 = expf(L[j] - M) / Z * L[j];
        float o2 = expf(L[j + 512] - M) / Z * L[j + 512];
        word[b * 512 + j] = o1 + o2;
    }
}

// ---- word2 ----
__global__ void k_txt(const float* __restrict__ word, const void* __restrict__ tw,
                      const void* __restrict__ tb, float* __restrict__ word2,
                      const void* __restrict__ img) {
    int isbf = detect_bf(img);
    int n = blockIdx.x, tid = threadIdx.x;
    __shared__ float wL[8][512];
    __shared__ float red[256 * 8];
    for (int e = tid; e < 4096; e += 256) wL[e >> 9][e & 511] = word[e];
    __syncthreads();
    float acc[8] = {0, 0, 0, 0, 0, 0, 0, 0};
    for (int c = tid; c < 512; c += 256) {
        float tv = inp(tw, (long)n * 512 + c, isbf);
        for (int b = 0; b < 8; ++b) acc[b] += wL[b][c] * tv;
    }
    for (int b = 0; b < 8; ++b) red[tid * 8 + b] = acc[b];
    __syncthreads();
    for (int s = 128; s > 0; s >>= 1) {
        if (tid < s) for (int b = 0; b < 8; ++b) red[tid * 8 + b] += red[(tid + s) * 8 + b];
        __syncthreads();
    }
    if (tid < 8) word2[tid * 2305 + n] = red[tid] + inp(tb, n, isbf);
}

// ---- eff_w / eff_b ----
__global__ void k_eff(const float* __restrict__ word2, const void* __restrict__ w3,
                      const void* __restrict__ b3, float* __restrict__ effw,
                      float* __restrict__ effb, const void* __restrict__ img) {
    int isbf = detect_bf(img);
    int bid = blockIdx.x;
    int b = bid / 9, tap = bid - b * 9;
    int tid = threadIdx.x;
    __shared__ float dw[256];
    dw[tid] = word2[b * 2305 + tid * 9 + tap];
    __syncthreads();
    float acc = 0.f;
#pragma unroll 4
    for (int c = 0; c < 256; ++c) acc += dw[c] * inp(w3, c * 256 + tid, isbf);
    effw[(b * 9 + tap) * 256 + tid] = acc;
    if (tid == 0) {
        float e = 0.f;
        for (int c = 0; c < 256; ++c) e += dw[c] * inp(b3, c, isbf);
        effb[b * 9 + tap] = e;
    }
}

// ---- epilogue helper for 32x32 C/D tiles: col=lane&31, row=(r&3)+8*(r>>2)+4*hi ----
__device__ __forceinline__ void epi32(const floatx16& Acc, int pxbase, int co4,
        int csh, int Cout, int tY, int tX, int b, int OW2, int hi,
        __hip_bfloat16* __restrict__ out, float& s1, float& s2) {
    int par = co4 >> csh; int co = co4 & (Cout - 1);
    int fyo = par >> 1, fxo = par & 1;
#pragma unroll
    for (int r = 0; r < 16; ++r) {
        int row = (r & 3) + 8 * (r >> 2) + 4 * hi;
        int px = pxbase + row;
        int fy = (((tY << 3) + (px >> 4)) << 1) + fyo;
        int fx = (((tX << 4) + (px & 15)) << 1) + fxo;
        float v = Acc[r];
        out[(((long)(b * OW2 + fy)) * OW2 + fx) * Cout + co] = F2BF(v);
        s1 += v; s2 += v * v;
    }
}

// ---- k_conv4 v7 (round-7 verified): weights loaded ONCE per block ----
__global__ __launch_bounds__(256, 3) void k_conv4(const __hip_bfloat16* __restrict__ in,
        const __hip_bfloat16* __restrict__ w4, __hip_bfloat16* __restrict__ out,
        int inH, int inW, int Cout, float* __restrict__ s1o, float* __restrict__ s2o,
        const float* __restrict__ bnS1, const float* __restrict__ bnS2,
        const void* __restrict__ g, const void* __restrict__ bb, float invN,
        const void* __restrict__ img) {
    int Cout4 = Cout << 2;
    int csh = (Cout == 512) ? 9 : 8;
    int G = Cout4 >> 5;
    int tXn = inW >> 4, tYn = inH >> 3;
    int bid = blockIdx.y;
    int tX = bid % tXn; int tmp = bid / tXn; int tY = tmp % tYn; int b = tmp / tYn;
    int co0 = blockIdx.x * 128;
    __shared__ __align__(16) __hip_bfloat16 Hs[4 * 1448];
    __shared__ float scT[512], shT[512];
    int tid = threadIdx.x;
    int l = tid & 63, l31 = l & 31, hi = l >> 5;
    int wave = tid >> 6;
    int dobn = (bnS1 != nullptr);
    if (dobn) {
        int isbf = detect_bf(img);
        for (int c = tid; c < 512; c += 256) {
            float m = bnS1[c] * invN, var = bnS2[c] * invN - m * m;
            float sc = inp(g, c, isbf) * rsqrtf(var + 1e-5f);
            scT[c] = sc; shT[c] = inp(bb, c, isbf) - m * sc;
        }
    }
    int R0 = (tY << 3) - 1, C0 = (tX << 4) - 1;
    long base = (long)b * inH * inW;
    int sub = tid & 3;
    const __hip_bfloat16* ga[3];
    int wo[3];
#pragma unroll
    for (int s = 0; s < 3; ++s) {
        int gi = tid + s * 256;
        int p = gi >> 2; if (p > 179) p = 179;
        int hy = p / 18, hx = p - hy * 18;
        int gr = R0 + hy; gr = gr < 0 ? 0 : (gr > inH - 1 ? inH - 1 : gr);
        int gc = C0 + hx; gc = gc < 0 ? 0 : (gc > inW - 1 ? inW - 1 : gc);
        ga[s] = in + (base + (long)gr * inW + gc) * 512 + sub * 8;
        wo[s] = sub * 1448 + p * 8;
    }
    int has2 = (tid < 208);
    short8 r0 = *(const short8*)(ga[0]);
    short8 r1 = *(const short8*)(ga[1]);
    short8 r2 = {0, 0, 0, 0, 0, 0, 0, 0};
    if (has2) r2 = *(const short8*)(ga[2]);
    int qA = hi * 1448;
    int qB = qA + 2896;
    int h[4];
#pragma unroll
    for (int i = 0; i < 4; ++i) {
        int px = i * 32 + l31;
        h[i] = ((px >> 4) * 18 + (px & 15)) * 8;
    }
    const __hip_bfloat16* wl2 = w4 + (long)l * 8;
    int cgw = (co0 >> 5) + wave;
    short8 wS0[2], wS1[2], wS2[2];
#define LDW(S, t, c) { long fb = (((long)((t) * 16 + (c)) * G + cgw) * 2) * 512; \
    S[0] = *(const short8*)(wl2 + fb); \
    S[1] = *(const short8*)(wl2 + fb + 512); }
    floatx16 zero16 = {0,0,0,0,0,0,0,0,0,0,0,0,0,0,0,0};
    floatx16 a[4];
#pragma unroll
    for (int i = 0; i < 4; ++i) a[i] = zero16;
    LDW(wS0, 0, 0);
    for (int ci0 = 0; ci0 < 512; ci0 += 32) {
        int cc = ci0 >> 5;
        __syncthreads();
        if (dobn) {
            float scv[8], shv[8];
#pragma unroll
            for (int k = 0; k < 8; ++k) { int c = ci0 + sub * 8 + k; scv[k] = scT[c]; shv[k] = shT[c]; }
#pragma unroll
            for (int k = 0; k < 8; ++k) {
                float f0 = bfbits2f(r0[k]) * scv[k] + shv[k]; r0[k] = f2bfbits(f0 > 0.f ? f0 : 0.f);
                float f1 = bfbits2f(r1[k]) * scv[k] + shv[k]; r1[k] = f2bfbits(f1 > 0.f ? f1 : 0.f);
                float f2 = bfbits2f(r2[k]) * scv[k] + shv[k]; r2[k] = f2bfbits(f2 > 0.f ? f2 : 0.f);
            }
        }
        *(short8*)(Hs + wo[0]) = r0;
        *(short8*)(Hs + wo[1]) = r1;
        if (has2) *(short8*)(Hs + wo[2]) = r2;
        __syncthreads();
        if (ci0 < 480) {
            r0 = *(const short8*)(ga[0] + ci0 + 32);
            r1 = *(const short8*)(ga[1] + ci0 + 32);
            if (has2) r2 = *(const short8*)(ga[2] + ci0 + 32);
        }
#pragma unroll
        for (int tap = 0; tap < 9; ++tap) {
            {
                int nt = tap + 1, ncc = cc;
                if (nt == 9) { nt = 0; ncc = cc + 1; }
                if (ncc < 16) {
                    if (((tap + 1) % 3) == 0)      { LDW(wS0, nt, ncc); }
                    else if (((tap + 1) % 3) == 1) { LDW(wS1, nt, ncc); }
                    else                            { LDW(wS2, nt, ncc); }
                }
            }
            int dy = tap / 3, dx = tap - dy * 3;
            int hoE = (dy * 18 + dx) * 8;
            if ((tap % 3) == 0) {
#pragma unroll
                for (int i = 0; i < 4; ++i) {
                    short8 af0 = *(const short8*)(Hs + qA + h[i] + hoE);
                    short8 af1 = *(const short8*)(Hs + qB + h[i] + hoE);
                    a[i] = __builtin_amdgcn_mfma_f32_32x32x16_bf16(af0, wS0[0], a[i], 0, 0, 0);
                    a[i] = __builtin_amdgcn_mfma_f32_32x32x16_bf16(af1, wS0[1], a[i], 0, 0, 0);
                }
            } else if ((tap % 3) == 1) {
#pragma unroll
                for (int i = 0; i < 4; ++i) {
                    short8 af0 = *(const short8*)(Hs + qA + h[i] + hoE);
                    short8 af1 = *(const short8*)(Hs + qB + h[i] + hoE);
                    a[i] = __builtin_amdgcn_mfma_f32_32x32x16_bf16(af0, wS1[0], a[i], 0, 0, 0);
                    a[i] = __builtin_amdgcn_mfma_f32_32x32x16_bf16(af1, wS1[1], a[i], 0, 0, 0);
                }
            } else {
#pragma unroll
                for (int i = 0; i < 4; ++i) {
                    short8 af0 = *(const short8*)(Hs + qA + h[i] + hoE);
                    short8 af1 = *(const short8*)(Hs + qB + h[i] + hoE);
                    a[i] = __builtin_amdgcn_mfma_f32_32x32x16_bf16(af0, wS2[0], a[i], 0, 0, 0);
                    a[i] = __builtin_amdgcn_mfma_f32_32x32x16_bf16(af1, wS2[1], a[i], 0, 0, 0);
                }
            }
        }
    }
#undef LDW
    int OW2 = inW << 1;
    float s1v = 0.f, s2v = 0.f;
    int co4w = co0 + wave * 32 + l31;
#pragma unroll
    for (int i = 0; i < 4; ++i)
        epi32(a[i], i * 32, co4w, csh, Cout, tY, tX, b, OW2, hi, out, s1v, s2v);
    s1v += __shfl_xor(s1v, 32); s2v += __shfl_xor(s2v, 32);
    if (hi == 0) {
        int ch = co4w & (Cout - 1);
        atomicAdd(s1o + ch, s1v);
        atomicAdd(s2o + ch, s2v);
    }
}

// ---- k_efix: boundary repair (16x16 MFMA path, unchanged semantics) ----
__global__ __launch_bounds__(256) void k_efix(const __hip_bfloat16* __restrict__ in,
        __hip_bfloat16* __restrict__ Y, const __hip_bfloat16* __restrict__ wRo,
        int inW, int Cout, int ebase,
        float* __restrict__ s1o, float* __restrict__ s2o) {
    int OW = inW << 1;
    int coT = Cout >> 6;
    int b = blockIdx.x / coT, cot = blockIdx.x - b * coT;
    int co0 = cot << 6;
    int e = ebase + blockIdx.y;   // 0 top, 1 bottom, 2 left, 3 right
    __shared__ __align__(16) __hip_bfloat16 E[130 * 40];
    __shared__ __align__(16) __hip_bfloat16 Lline[64 * 32];
    int tid = threadIdx.x;
    int wave = tid >> 6, l = tid & 63, lm = l & 15, q = l >> 4;
    int mspan = OW >> 2;
    int ilim = OW >> 6;
    int mb = wave * mspan;
    floatx4 zero4 = {0.f, 0.f, 0.f, 0.f};
    floatx4 acc[2][4];
    for (int i = 0; i < 2; ++i) for (int j = 0; j < 4; ++j) acc[i][j] = zero4;
    int lineG = inW * 4;
    int eG = (OW + 2) * 4;
    int haveL = (tid < lineG);
    const __hip_bfloat16* lbase = in;
    {
        int x = tid >> 2, sb = tid & 3;
        long gidx;
        if (e < 2) { int R = (e == 0) ? 0 : inW - 1; gidx = (long)(b * inW + R) * inW + x; }
        else       { int Cc = (e == 2) ? 0 : inW - 1; gidx = (long)(b * inW + x) * inW + Cc; }
        if (x >= inW) gidx = (long)b * inW * inW;
        lbase = in + gidx * 512 + sb * 8;
    }
    short8 rl = {0, 0, 0, 0, 0, 0, 0, 0};
    if (haveL) rl = *(const short8*)(lbase);
    for (int ci0 = 0; ci0 < 512; ci0 += 32) {
        __syncthreads();
        if (haveL) *(short8*)(Lline + tid * 8) = rl;
        __syncthreads();
        if (ci0 < 480 && haveL) rl = *(const short8*)(lbase + ci0 + 32);
        for (int t = tid; t < eG; t += 256) {
            int f1 = t >> 2, sb = t & 3;
            int f = f1 - 1;
            short8 res = {0, 0, 0, 0, 0, 0, 0, 0};
            if (f < 0 || f >= OW) {
                if (e < 2) { int xx = (f < 0) ? 0 : inW - 1; res = *(const short8*)(Lline + (xx * 4 + sb) * 8); }
            } else {
                int x0; float w0;
                if (f & 1) { x0 = f >> 1; w0 = 0.75f; } else { x0 = (f >> 1) - 1; w0 = 0.25f; }
                int x1 = x0 + 1;
                if (x0 < 0) x0 = 0;
                if (x1 > inW - 1) x1 = inW - 1;
                short8 v0 = *(const short8*)(Lline + (x0 * 4 + sb) * 8);
                short8 v1 = *(const short8*)(Lline + (x1 * 4 + sb) * 8);
                float w1c = 1.f - w0;
#pragma unroll
                for (int k = 0; k < 8; ++k)
                    res[k] = f2bfbits(w0 * bfbits2f(v0[k]) + w1c * bfbits2f(v1[k]));
            }
            *(short8*)(E + f1 * 40 + sb * 8) = res;
        }
        __syncthreads();
        int cc = ci0 >> 5;
#pragma unroll
        for (int t = 0; t < 3; ++t) {
            int tap = (e == 0) ? t : (e == 1) ? (6 + t) : (e == 2) ? (t * 3) : (t * 3 + 2);
            short8 bfv[4];
#pragma unroll
            for (int j = 0; j < 4; ++j)
                bfv[j] = *(const short8*)(wRo + ((long)(tap * 16 + cc) * Cout + co0 + j * 16 + lm) * 32 + q * 8);
#pragma unroll
            for (int i = 0; i < 2; ++i) {
                if (i < ilim) {
                    short8 af = *(const short8*)(E + (mb + i * 16 + lm + t) * 40 + q * 8);
#pragma unroll
                    for (int j = 0; j < 4; ++j)
                        acc[i][j] = __builtin_amdgcn_mfma_f32_16x16x32_bf16(af, bfv[j], acc[i][j], 0, 0, 0);
                }
            }
        }
    }
    float d1s[4] = {0.f, 0.f, 0.f, 0.f}, d2s[4] = {0.f, 0.f, 0.f, 0.f};
    for (int i = 0; i < ilim; ++i)
#pragma unroll
    for (int j = 0; j < 4; ++j) {
        int co = co0 + j * 16 + lm;
#pragma unroll
        for (int r = 0; r < 4; ++r) {
            int m = mb + i * 16 + q * 4 + r;
            int fy, fx;
            if (e == 0) { fy = 0; fx = m; }
            else if (e == 1) { fy = OW - 1; fx = m; }
            else if (e == 2) { fy = m; fx = 0; }
            else { fy = m; fx = OW - 1; }
            long a = (((long)(b * OW + fy)) * OW + fx) * Cout + co;
            float vo = BF2F(Y[a]);
            float vn = vo - acc[i][j][r];
            Y[a] = F2BF(vn);
            d1s[j] += vn - vo;
            d2s[j] += vn * vn - vo * vo;
        }
    }
#pragma unroll
    for (int j = 0; j < 4; ++j) {
        d1s[j] += __shfl_xor(d1s[j], 16); d1s[j] += __shfl_xor(d1s[j], 32);
        d2s[j] += __shfl_xor(d2s[j], 16); d2s[j] += __shfl_xor(d2s[j], 32);
    }
    if (q == 0) {
#pragma unroll
        for (int j = 0; j < 4; ++j) {
            atomicAdd(s1o + co0 + j * 16 + lm, d1s[j]);
            atomicAdd(s2o + co0 + j * 16 + lm, d2s[j]);
        }
    }
}

// ---- masks ----
__global__ __launch_bounds__(256) void k_masks(const __hip_bfloat16* __restrict__ x2,
                                               const float* __restrict__ effw,
                                               const float* __restrict__ effb,
                                               const float* __restrict__ word2,
                                               void* __restrict__ mout,
                                               const float* __restrict__ s1,
                                               const float* __restrict__ s2,
                                               const void* __restrict__ g,
                                               const void* __restrict__ bb, float invN,
                                               const void* __restrict__ img) {
    int isbf = detect_bf(img);
    int bid = blockIdx.x;
    int tX = bid & 15, tY = (bid >> 4) & 15, b = bid >> 8;
    __shared__ __align__(16) __hip_bfloat16 H[100 * 264];
    __shared__ __align__(16) float EW[9 * 256];
    __shared__ float EB[9];
    __shared__ float sc2T[256];
    __shared__ float sh2T[256];
    int tid = threadIdx.x;
    {
        float m = s1[tid] * invN, var = s2[tid] * invN - m * m;
        float sc = inp(g, tid, isbf) * rsqrtf(var + 1e-5f);
        sc2T[tid] = sc; sh2T[tid] = inp(bb, tid, isbf) - m * sc;
    }
    __syncthreads();
    for (int e = tid; e < 3200; e += 256) {
        int c8 = e & 31, p = e >> 5;
        int hy = p / 10, hx = p - hy * 10;
        int gy = tY * 8 + hy - 1, gx = tX * 8 + hx - 1;
        short8 res = {0, 0, 0, 0, 0, 0, 0, 0};
        if (gy >= 0 && gy < 128 && gx >= 0 && gx < 128) {
            short8 raw = *(const short8*)(x2 + (((long)(b * 128 + gy)) * 128 + gx) * 256 + c8 * 8);
#pragma unroll
            for (int k = 0; k < 8; ++k) {
                int c = c8 * 8 + k;
                float v = bfbits2f(raw[k]) * sc2T[c] + sh2T[c];
                res[k] = f2bfbits(v > 0.f ? v : 0.f);
            }
        }
        *(short8*)(H + p * 264 + c8 * 8) = res;
    }
    for (int e = tid; e < 2304; e += 256) EW[e] = effw[b * 2304 + e];
    if (tid < 9) EB[tid] = effb[b * 9 + tid];
    __syncthreads();
    int px = tid & 63, part = tid >> 6;
    int py = px >> 3, pxc = px & 7;
    int cbase = part * 64;
    float acc = 0.f;
    for (int tap = 0; tap < 9; ++tap) {
        int ky = tap / 3, kx = tap - ky * 3;
        int hp = (py + ky) * 10 + pxc + kx;
        const __hip_bfloat16* hrow = H + (long)hp * 264 + cbase;
        const float* erow = EW + tap * 256 + cbase;
#pragma unroll
        for (int c8 = 0; c8 < 8; ++c8) {
            short8 h8 = *(const short8*)(hrow + c8 * 8);
            floatx4 e0 = *(const floatx4*)(erow + c8 * 8);
            floatx4 e1 = *(const floatx4*)(erow + c8 * 8 + 4);
            acc += bfbits2f(h8[0]) * e0[0] + bfbits2f(h8[1]) * e0[1] +
                   bfbits2f(h8[2]) * e0[2] + bfbits2f(h8[3]) * e0[3] +
                   bfbits2f(h8[4]) * e1[0] + bfbits2f(h8[5]) * e1[1] +
                   bfbits2f(h8[6]) * e1[2] + bfbits2f(h8[7]) * e1[3];
        }
    }
    float (*red)[64] = (float(*)[64])sc2T;
    red[part][px] = acc;
    __syncthreads();
    if (part == 0) {
        float s = red[0][px] + red[1][px] + red[2][px] + red[3][px];
        int oy = tY * 8 + py, ox = tX * 8 + pxc;
        float bias = word2[b * 2305 + 2304];
        for (int tap = 0; tap < 9; ++tap) {
            int ky = tap / 3, kx = tap - ky * 3;
            int iy = oy + ky - 1, ix = ox + kx - 1;
            if (iy >= 0 && iy < 128 && ix >= 0 && ix < 128) bias += EB[tap];
        }
        outw(mout, b * 16384 + oy * 128 + ox, s + bias, isbf);
    }
}

// ---- hid ----
__global__ void k_hid(const float* __restrict__ qa, const void* __restrict__ w1,
                      const void* __restrict__ b1, float* __restrict__ hid,
                      const void* __restrict__ img) {
    int isbf = detect_bf(img);
    int b = blockIdx.x, ht = blockIdx.y, tid = threadIdx.x;
    __shared__ float qL[1024];
    __shared__ float R[256];
    for (int j = tid; j < 1024; j += 256) qL[j] = qa[b * 1024 + j];
    __syncthreads();
    int h = ht * 64 + (tid >> 2), cl = tid & 3;
    float acc = 0.f;
#pragma unroll 4
    for (int k = 0; k < 256; ++k) {
        int c = cl + 4 * k;
        acc += qL[c] * inp(w1, (long)h * 1024 + c, isbf);
    }
    R[tid] = acc;
    __syncthreads();
    if (cl == 0) {
        float v = R[tid] + R[tid + 1] + R[tid + 2] + R[tid + 3] + inp(b1, h, isbf);
        hid[b * 256 + h] = v > 0.f ? v : 0.f;
    }
}

// ---- logits: PARALLEL form (gates 8 MACs/lane, experts 184 threads x 128) ----
__global__ void k_logits(const float* __restrict__ hid, const float* __restrict__ ansv,
                         const void* __restrict__ w2, const void* __restrict__ b2,
                         const void* __restrict__ lw2, const void* __restrict__ lb2,
                         const void* __restrict__ ew, const void* __restrict__ ebias,
                         void* __restrict__ out, const void* __restrict__ img) {
    int isbf = detect_bf(img);
    int b = blockIdx.x, tid = threadIdx.x;
    __shared__ float hidL[256], avL[512], gates[8], feat[128], dv[184];
    hidL[tid] = hid[b * 256 + tid];
    for (int j = tid; j < 512; j += 256) avL[j] = ansv[b * 512 + j];
    __syncthreads();
    // gates: e = tid>>5, part = tid&31 (8 MACs + 32-lane shfl reduce)
    {
        int e = tid >> 5, part = tid & 31;
        float ga = 0.f;
#pragma unroll
        for (int j = 0; j < 8; ++j)
            ga += hidL[part + j * 32] * inp(w2, e * 256 + part + j * 32, isbf);
        for (int off = 16; off; off >>= 1) ga += __shfl_xor(ga, off);
        if (part == 0) gates[e] = ga + inp(b2, e, isbf);
    }
    // feat: f = tid>>1, half = tid&1 (256 MACs, unrolled)
    {
        int f = tid >> 1, half = tid & 1;
        float acc = 0.f;
#pragma unroll 4
        for (int k = 0; k < 256; ++k) {
            int c = half + 2 * k;
            acc += avL[c] * inp(lw2, (long)f * 512 + c, isbf);
        }
        acc += __shfl_xor(acc, 1);
        if (half == 0) feat[f] = acc + inp(lb2, f, isbf);
    }
    __syncthreads();
    if (tid == 0) {
        float mx = gates[0];
        for (int e = 1; e < 8; ++e) mx = fmaxf(mx, gates[e]);
        float z = 0.f;
        for (int e = 0; e < 8; ++e) { gates[e] = expf(gates[e] - mx); z += gates[e]; }
        for (int e = 0; e < 8; ++e) gates[e] /= z;
    }
    if (tid < 184) {
        int e = tid / 23, o = tid - e * 23;
        float d = inp(ebias, e * 23 + o, isbf);
#pragma unroll 4
        for (int ff = 0; ff < 128; ++ff)
            d += inp(ew, (long)(e * 23 + o) * 128 + ff, isbf) * feat[ff];
        dv[tid] = d;
    }
    __syncthreads();
    if (tid < 23) {
        float a = 0.f;
#pragma unroll
        for (int e = 0; e < 8; ++e) a += gates[e] * dv[e * 23 + tid];
        outw(out, OUT_LOGITS + b * 23 + tid, a, isbf);
    }
}

extern "C" void kernel_launch(void* const* d_in, const int* in_sizes, int n_in,
                              void* d_out, int out_size, void* d_ws, size_t ws_size,
                              hipStream_t stream) {
    (void)in_sizes; (void)n_in; (void)out_size; (void)ws_size;
    const void* img   = d_in[0];
    const void* state = d_in[2];
    const void* Wt    = d_in[4];
    const void* cw1   = d_in[7];
    const void* g1    = d_in[8];
    const void* bb1   = d_in[9];
    const void* cw2   = d_in[10];
    const void* g2    = d_in[11];
    const void* bb2   = d_in[12];
    const void* w3    = d_in[13];
    const void* b3    = d_in[14];
    const void* txtw  = d_in[15];
    const void* txtb  = d_in[16];
    const void* lnw   = d_in[17];
    const void* lnb   = d_in[18];
    const void* lnw2  = d_in[19];
    const void* lnb2  = d_in[20];
    const void* rw1   = d_in[21];
    const void* rb1   = d_in[22];
    const void* rw2   = d_in[23];
    const void* rb2   = d_in[24];
    const void* ew    = d_in[25];
    const void* eb    = d_in[26];

    char* ws = (char*)d_ws;
    __hip_bfloat16* W4R2 = (__hip_bfloat16*)(ws + WS_W4R2);
    __hip_bfloat16* WRO2 = (__hip_bfloat16*)(ws + WS_WRO2);
    __hip_bfloat16* WRO1 = (__hip_bfloat16*)(ws + WS_WRO1);
    __hip_bfloat16* Y1   = (__hip_bfloat16*)(ws + WS_Y1);
    __hip_bfloat16* Y2   = (__hip_bfloat16*)(ws + WS_Y2);
    __hip_bfloat16* W4R1 = (__hip_bfloat16*)(ws + WS_W4R1);
    __hip_bfloat16* A    = (__hip_bfloat16*)(ws + WS_A);
    __hip_bfloat16* WTB  = (__hip_bfloat16*)(ws + WS_WTB);
    __hip_bfloat16* SRCB = (__hip_bfloat16*)(ws + WS_SRCB);
    float* S1A = (float*)(ws + WS_STATS);
    float* S2A = S1A + 512;
    float* S1B = S1A + 1024;
    float* S2B = S1A + 1536;
    float* ANS   = (float*)(ws + WS_ANS);
    float* QA    = (float*)(ws + WS_QA);
    float* ANSV  = (float*)(ws + WS_ANSV);
    float* WORD  = (float*)(ws + WS_WORD);
    float* WORD2 = (float*)(ws + WS_WORD2);
    float* EFFW  = (float*)(ws + WS_EFFW);
    float* EFFB  = (float*)(ws + WS_EFFB);
    float* HID   = (float*)(ws + WS_HID);

    k_pre<<<5889, 256, 0, stream>>>(img, cw1, cw2, Wt, A, W4R1, W4R2, WRO1, WRO2, WTB,
                                    (float*)(ws + WS_STATS));
    k_gemm1<<<dim3(64, 4), 256, 0, stream>>>(A, WTB, SRCB, d_out, ANS, img);
    k_ansvec<<<dim3(8, 8), 256, 0, stream>>>(ANS, lnw, lnb, ANSV, img);
    k_word<<<8, 256, 0, stream>>>(ANSV, state, QA, WORD, img);
    k_txt<<<2305, 256, 0, stream>>>(WORD, txtw, txtb, WORD2, img);
    k_eff<<<72, 256, 0, stream>>>(WORD2, w3, b3, EFFW, EFFB, img);
    // conv1: composed at orig res 32x32 (128px x 128co4 blocks), Cout4=2048
    k_conv4<<<dim3(16, 64), 256, 0, stream>>>(SRCB, W4R1, Y1, 32, 32, 512, S1A, S2A,
                                              nullptr, nullptr, nullptr, nullptr, 0.f, img);
    k_efix<<<dim3(64, 2), 256, 0, stream>>>(SRCB, Y1, WRO1, 32, 512, 0, S1A, S2A);
    k_efix<<<dim3(64, 2), 256, 0, stream>>>(SRCB, Y1, WRO1, 32, 512, 2, S1A, S2A);
    // conv2: composed at orig res 64x64, Cout4=1024, bn1+relu fused into halo staging
    k_conv4<<<dim3(8, 256), 256, 0, stream>>>(Y1, W4R2, Y2, 64, 64, 256, S1B, S2B,
                                              S1A, S2A, g1, bb1, 1.f / 32768.f, img);
    k_efix<<<dim3(32, 2), 256, 0, stream>>>(Y1, Y2, WRO2, 64, 256, 0, S1B, S2B);
    k_efix<<<dim3(32, 2), 256, 0, stream>>>(Y1, Y2, WRO2, 64, 256, 2, S1B, S2B);
    k_masks<<<2048, 256, 0, stream>>>(Y2, EFFW, EFFB, WORD2, d_out,
                                      S1B, S2B, g2, bb2, 1.f / 131072.f, img);
    k_hid<<<dim3(8, 4), 256, 0, stream>>>(QA, rw1, rb1, HID, img);
    k_logits<<<8, 256, 0, stream>>>(HID, ANSV, rw2, rb2, lnw2, lnb2, ew, eb, d_out, img);
}

// Round 11
// 984.794 us; speedup vs baseline: 1.1929x; 1.0305x over previous
//
#include <hip/hip_runtime.h>
#include <hip/hip_bf16.h>

typedef __attribute__((ext_vector_type(8))) short short8;
typedef __attribute__((ext_vector_type(4))) short shortx4;
typedef __attribute__((ext_vector_type(4))) float floatx4;
typedef __attribute__((ext_vector_type(16))) float floatx16;

#define F2BF __float2bfloat16
#define BF2F __bfloat162float

// ---------------- workspace layout (byte offsets), total ~112.0 MiB ----------------
#define WS_W4R2   0UL
#define WS_WRO2   9437184UL
#define WS_WRO1   11796480UL
#define WS_Y1     16515072UL
#define WS_Y2     50069504UL
#define WS_W4R1   50069504UL
#define WS_A      68943872UL
#define WS_WTB    77332480UL
#define WS_SRCB   77856768UL
#define WS_STATS  117178368UL
#define WS_ANS    117186560UL
#define WS_QA     117207040UL
#define WS_ANSV   117239808UL
#define WS_WORD   117256192UL
#define WS_WORD2  117272576UL
#define WS_EFFW   117346336UL
#define WS_EFFB   117420064UL
#define WS_HID    117420352UL

#define OUT_LOGITS 131072
#define OUT_SRC    131256

__device__ __forceinline__ float inp(const void* p, long i, int isbf) {
    return isbf ? BF2F(((const __hip_bfloat16*)p)[i]) : ((const float*)p)[i];
}
__device__ __forceinline__ void outw(void* p, long i, float v, int isbf) {
    if (isbf) ((__hip_bfloat16*)p)[i] = F2BF(v);
    else      ((float*)p)[i] = v;
}
__device__ __forceinline__ float bfbits2f(short s) {
    unsigned int u = ((unsigned int)(unsigned short)s) << 16;
    float f; __builtin_memcpy(&f, &u, 4); return f;
}
__device__ __forceinline__ short f2bfbits(float f) {
    __hip_bfloat16 h = F2BF(f);
    short s; __builtin_memcpy(&s, &h, 2); return s;
}

__device__ __forceinline__ int detect_bf(const void* img) {
    const unsigned short* u = (const unsigned short*)img;
    int l = threadIdx.x & 63;
    int c = 0;
#pragma unroll
    for (int k = 0; k < 8; ++k) {
        int e = (u[(l * 8 + k) * 2] >> 7) & 0xFF;
        c += (e >= 100 && e <= 150) ? 1 : 0;
    }
    for (int off = 32; off; off >>= 1) c += __shfl_xor(c, off, 64);
    return c > 307;
}

// ---- fused prep (+ stats zeroing block) ----
// W4 layout (fragment-contiguous): [tap][cc(16)][cog(Cout4/32)][ksub(2)][lane(64)][8ci]
__global__ void k_pre(const void* __restrict__ img, const void* __restrict__ cw1,
                      const void* __restrict__ cw2, const void* __restrict__ Wt,
                      __hip_bfloat16* __restrict__ A,
                      __hip_bfloat16* __restrict__ W4R1, __hip_bfloat16* __restrict__ W4R2,
                      __hip_bfloat16* __restrict__ WRo1, __hip_bfloat16* __restrict__ WRo2,
                      __hip_bfloat16* __restrict__ WTB, float* __restrict__ STZ) {
    int isbf = detect_bf(img);
    int bid = blockIdx.x, tid = threadIdx.x;
    __shared__ float LS[2304];
    if (bid < 4096) {
        int nt = bid & 31, ct = (bid >> 5) & 15, b = bid >> 9;
        int tx = tid & 31, ty = tid >> 5;
        int c0 = ct * 32, n0 = nt * 32;
        for (int j = 0; j < 4; ++j) {
            int c = c0 + ty + j * 8;
            LS[(ty + j * 8) * 33 + tx] = inp(img, ((long)(b * 512 + c)) * 1024 + n0 + tx, isbf);
        }
        __syncthreads();
        // pe hoist: c is fixed per thread in the write loop
        int c = c0 + tx;
        int iw = ((c < 256) ? c : (c - 256)) >> 1;
        float ediv = expf(-0.0719557841560639f * (float)iw);
        for (int j = 0; j < 4; ++j) {
            int n = n0 + ty + j * 8;
            float pos = (c < 256) ? (float)(n & 31) : (float)(n >> 5);
            float ang = pos * ediv;
            float pe = (c & 1) ? cosf(ang) : sinf(ang);
            A[((long)(b * 1024 + n)) * 512 + c] = F2BF(LS[tx * 33 + ty + j * 8] + pe);
        }
    } else if (bid < 5632) {
        int bb = bid - 4096;
        const void* w; __hip_bfloat16 *w4, *wo; int Cout, r0;
        if (bb < 1024) { w = cw1; w4 = W4R1; wo = WRo1; Cout = 512; r0 = bb * 256; }
        else           { w = cw2; w4 = W4R2; wo = WRo2; Cout = 256; r0 = (bb - 1024) * 256; }
        int Cout4 = Cout << 2;
        int G = Cout4 >> 5;
        int co = r0 >> 9, ci0 = r0 & 511;
        for (int e = tid; e < 2304; e += 256) LS[e] = inp(w, (long)r0 * 9 + e, isbf);
        __syncthreads();
        int ci = ci0 + tid;
        int cc = ci >> 5, cw = ci & 31;
        int ksub = (ci >> 4) & 1, hic = (ci >> 3) & 1, ee = ci & 7;
        float w9[9];
#pragma unroll
        for (int t = 0; t < 9; ++t) w9[t] = LS[tid * 9 + t];
#pragma unroll
        for (int t = 0; t < 9; ++t)
            wo[((long)(t * 16 + cc) * Cout + co) * 32 + cw] = F2BF(w9[t]);
        const float BY[2][3][3] = {{{0.75f, 0.25f, 0.f}, {0.25f, 0.75f, 0.75f}, {0.f, 0.f, 0.25f}},
                                   {{0.25f, 0.f, 0.f},  {0.75f, 0.75f, 0.25f}, {0.f, 0.25f, 0.75f}}};
#pragma unroll
        for (int p = 0; p < 4; ++p) {
            int py = p >> 1, px = p & 1;
            int co4 = p * Cout + co;
            int cog = co4 >> 5, l31c = co4 & 31;
#pragma unroll
            for (int dy = 0; dy < 3; ++dy)
#pragma unroll
            for (int dx = 0; dx < 3; ++dx) {
                float v = 0.f;
#pragma unroll
                for (int ky = 0; ky < 3; ++ky)
#pragma unroll
                for (int kx = 0; kx < 3; ++kx)
                    v += BY[py][dy][ky] * BY[px][dx][kx] * w9[ky * 3 + kx];
                long fi = ((((long)((dy * 3 + dx) * 16 + cc) * G + cog) * 2 + ksub) * 64
                           + hic * 32 + l31c) * 8 + ee;
                w4[fi] = F2BF(v);
            }
        }
    } else if (bid < 5888) {
        for (int i = (bid - 5632) * 256 + tid; i < 512 * 512; i += 256 * 256)
            WTB[i] = F2BF(inp(Wt, i, isbf));
    } else {
        for (int i = tid; i < 6144; i += 256) STZ[i] = 0.f;   // stats + ANS zero
    }
}

// ---- MFMA GEMM + fused epilogue (reg-prefetch staging) ----
__global__ __launch_bounds__(256) void k_gemm1(const __hip_bfloat16* __restrict__ A,
                                               const __hip_bfloat16* __restrict__ Bw,
                                               __hip_bfloat16* __restrict__ srcB,
                                               void* __restrict__ dst,
                                               float* __restrict__ ANS,
                                               const void* __restrict__ img) {
    int isbf = detect_bf(img);
    __shared__ __align__(16) __hip_bfloat16 As[128 * 32];
    __shared__ __align__(16) __hip_bfloat16 Bs[128 * 32];
    int m0 = blockIdx.x * 128, n0 = blockIdx.y * 128;
    int tid = threadIdx.x;
    int wave = tid >> 6, l = tid & 63, lm = l & 15, q = l >> 4;
    int wm = wave & 1, wn = wave >> 1;
    int m_0 = tid >> 2, qq0 = tid & 3;
    int m_1 = (tid + 256) >> 2, qq1 = qq0;
    const __hip_bfloat16* aA0 = A + ((long)(m0 + m_0)) * 512 + qq0 * 8;
    const __hip_bfloat16* aB0 = Bw + ((long)(n0 + m_0)) * 512 + qq0 * 8;
    const __hip_bfloat16* aA1 = A + ((long)(m0 + m_1)) * 512 + qq1 * 8;
    const __hip_bfloat16* aB1 = Bw + ((long)(n0 + m_1)) * 512 + qq1 * 8;
    int wA0 = m_0 * 32 + qq0 * 8, wA1 = m_1 * 32 + qq1 * 8;
    short8 rA0 = *(const short8*)(aA0), rB0 = *(const short8*)(aB0);
    short8 rA1 = *(const short8*)(aA1), rB1 = *(const short8*)(aB1);
    floatx4 zero4 = {0.f, 0.f, 0.f, 0.f};
    floatx4 acc[4][4];
    for (int i = 0; i < 4; ++i) for (int j = 0; j < 4; ++j) acc[i][j] = zero4;
    for (int k0 = 0; k0 < 512; k0 += 32) {
        __syncthreads();
        *(short8*)(As + wA0) = rA0; *(short8*)(Bs + wA0) = rB0;
        *(short8*)(As + wA1) = rA1; *(short8*)(Bs + wA1) = rB1;
        __syncthreads();
        if (k0 < 480) {
            rA0 = *(const short8*)(aA0 + k0 + 32); rB0 = *(const short8*)(aB0 + k0 + 32);
            rA1 = *(const short8*)(aA1 + k0 + 32); rB1 = *(const short8*)(aB1 + k0 + 32);
        }
        short8 af[4], bfv[4];
#pragma unroll
        for (int t = 0; t < 4; ++t) af[t] = *(short8*)(As + (wm * 64 + t * 16 + lm) * 32 + q * 8);
#pragma unroll
        for (int t = 0; t < 4; ++t) bfv[t] = *(short8*)(Bs + (wn * 64 + t * 16 + lm) * 32 + q * 8);
#pragma unroll
        for (int i = 0; i < 4; ++i)
#pragma unroll
            for (int j = 0; j < 4; ++j)
                acc[i][j] = __builtin_amdgcn_mfma_f32_16x16x32_bf16(af[i], bfv[j], acc[i][j], 0, 0, 0);
    }
    int b = m0 >> 10, hw0 = m0 & 1023;
    float cs[4] = {0.f, 0.f, 0.f, 0.f};
#pragma unroll
    for (int i = 0; i < 4; ++i)
#pragma unroll
        for (int j = 0; j < 4; ++j) {
            int mrow = wm * 64 + i * 16 + q * 4;
            int n = n0 + wn * 64 + j * 16 + lm;
            long mg = (long)(m0 + mrow);
#pragma unroll
            for (int r = 0; r < 4; ++r) {
                float v = acc[i][j][r];
                srcB[(mg + r) * 512 + n] = F2BF(v);
                cs[j] += v;
            }
            long obase = (long)OUT_SRC + ((long)(b * 512 + n)) * 1024 + hw0 + mrow;
            if (isbf) {
                shortx4 pk = { f2bfbits(acc[i][j][0]), f2bfbits(acc[i][j][1]),
                               f2bfbits(acc[i][j][2]), f2bfbits(acc[i][j][3]) };
                *(shortx4*)((__hip_bfloat16*)dst + obase) = pk;
            } else {
                floatx4 pk = { acc[i][j][0], acc[i][j][1], acc[i][j][2], acc[i][j][3] };
                *(floatx4*)((float*)dst + obase) = pk;
            }
        }
#pragma unroll
    for (int j = 0; j < 4; ++j) {
        cs[j] += __shfl_xor(cs[j], 16);
        cs[j] += __shfl_xor(cs[j], 32);
    }
    __syncthreads();
    float* CS = (float*)Bs;
    if (wm == 1 && q == 0) {
#pragma unroll
        for (int j = 0; j < 4; ++j) CS[wn * 64 + j * 16 + lm] = cs[j];
    }
    __syncthreads();
    if (wm == 0 && q == 0) {
#pragma unroll
        for (int j = 0; j < 4; ++j) {
            int n = n0 + wn * 64 + j * 16 + lm;
            atomicAdd(ANS + b * 512 + n, cs[j] + CS[wn * 64 + j * 16 + lm]);
        }
    }
}

// ---- ansv ----
__global__ void k_ansvec(const float* __restrict__ ANS, const void* __restrict__ lw,
                         const void* __restrict__ lb, float* __restrict__ ansv,
                         const void* __restrict__ img) {
    int isbf = detect_bf(img);
    int b = blockIdx.x, dt = blockIdx.y, tid = threadIdx.x;
    __shared__ float aL[512];
    __shared__ float R[256];
    aL[tid] = ANS[b * 512 + tid] * (1.f / 1024.f);
    aL[tid + 256] = ANS[b * 512 + tid + 256] * (1.f / 1024.f);
    __syncthreads();
    int d = dt * 64 + (tid >> 2), cl = tid & 3;
    float acc = 0.f;
#pragma unroll 4
    for (int k = 0; k < 128; ++k) {
        int c = cl + 4 * k;
        acc += aL[c] * inp(lw, (long)d * 512 + c, isbf);
    }
    R[tid] = acc;
    __syncthreads();
    if (cl == 0)
        ansv[b * 512 + d] = R[tid] + R[tid + 1] + R[tid + 2] + R[tid + 3] + inp(lb, d, isbf);
}

// ---- word/qa ----
__global__ void k_word(const float* __restrict__ ansv, const void* __restrict__ state,
                       float* __restrict__ qa, float* __restrict__ word,
                       const void* __restrict__ img) {
    int isbf = detect_bf(img);
    int b = blockIdx.x, tid = threadIdx.x;
    __shared__ float L[1024];
    __shared__ float red[256];
    L[tid] = inp(state, b * 512 + tid, isbf);
    L[tid + 256] = inp(state, b * 512 + tid + 256, isbf);
    L[tid + 512] = ansv[b * 512 + tid];
    L[tid + 768] = ansv[b * 512 + tid + 256];
    __syncthreads();
    for (int j = tid; j < 1024; j += 256) qa[b * 1024 + j] = L[j];
    float m = fmaxf(fmaxf(L[tid], L[tid + 256]), fmaxf(L[tid + 512], L[tid + 768]));
    red[tid] = m; __syncthreads();
    for (int s = 128; s > 0; s >>= 1) { if (tid < s) red[tid] = fmaxf(red[tid], red[tid + s]); __syncthreads(); }
    float M = red[0]; __syncthreads();
    float z = expf(L[tid] - M) + expf(L[tid + 256] - M) + expf(L[tid + 512] - M) + expf(L[tid + 768] - M);
    red[tid] = z; __syncthreads();
    for (int s = 128; s > 0; s >>= 1) { if (tid < s) red[tid] += red[tid + s]; __syncthreads(); }
    float Z = red[0];
    for (int j = tid; j < 512; j += 256) {
        float o1 = expf(L[j] - M) / Z * L[j];
        float o2 = expf(L[j + 512] - M) / Z * L[j + 512];
        word[b * 512 + j] = o1 + o2;
    }
}

// ---- word2 ----
__global__ void k_txt(const float* __restrict__ word, const void* __restrict__ tw,
                      const void* __restrict__ tb, float* __restrict__ word2,
                      const void* __restrict__ img) {
    int isbf = detect_bf(img);
    int n = blockIdx.x, tid = threadIdx.x;
    __shared__ float wL[8][512];
    __shared__ float red[256 * 8];
    for (int e = tid; e < 4096; e += 256) wL[e >> 9][e & 511] = word[e];
    __syncthreads();
    float acc[8] = {0, 0, 0, 0, 0, 0, 0, 0};
    for (int c = tid; c < 512; c += 256) {
        float tv = inp(tw, (long)n * 512 + c, isbf);
        for (int b = 0; b < 8; ++b) acc[b] += wL[b][c] * tv;
    }
    for (int b = 0; b < 8; ++b) red[tid * 8 + b] = acc[b];
    __syncthreads();
    for (int s = 128; s > 0; s >>= 1) {
        if (tid < s) for (int b = 0; b < 8; ++b) red[tid * 8 + b] += red[(tid + s) * 8 + b];
        __syncthreads();
    }
    if (tid < 8) word2[tid * 2305 + n] = red[tid] + inp(tb, n, isbf);
}

// ---- eff_w / eff_b ----
__global__ void k_eff(const float* __restrict__ word2, const void* __restrict__ w3,
                      const void* __restrict__ b3, float* __restrict__ effw,
                      float* __restrict__ effb, const void* __restrict__ img) {
    int isbf = detect_bf(img);
    int bid = blockIdx.x;
    int b = bid / 9, tap = bid - b * 9;
    int tid = threadIdx.x;
    __shared__ float dw[256];
    dw[tid] = word2[b * 2305 + tid * 9 + tap];
    __syncthreads();
    float acc = 0.f;
#pragma unroll 4
    for (int c = 0; c < 256; ++c) acc += dw[c] * inp(w3, c * 256 + tid, isbf);
    effw[(b * 9 + tap) * 256 + tid] = acc;
    if (tid == 0) {
        float e = 0.f;
        for (int c = 0; c < 256; ++c) e += dw[c] * inp(b3, c, isbf);
        effb[b * 9 + tap] = e;
    }
}

// ---- epilogue helper for 32x32 C/D tiles: col=lane&31, row=(r&3)+8*(r>>2)+4*hi ----
__device__ __forceinline__ void epi32(const floatx16& Acc, int pxbase, int co4,
        int csh, int Cout, int tY, int tX, int b, int OW2, int hi,
        __hip_bfloat16* __restrict__ out, float& s1, float& s2) {
    int par = co4 >> csh; int co = co4 & (Cout - 1);
    int fyo = par >> 1, fxo = par & 1;
#pragma unroll
    for (int r = 0; r < 16; ++r) {
        int row = (r & 3) + 8 * (r >> 2) + 4 * hi;
        int px = pxbase + row;
        int fy = (((tY << 3) + (px >> 4)) << 1) + fyo;
        int fx = (((tX << 4) + (px & 15)) << 1) + fxo;
        float v = Acc[r];
        out[(((long)(b * OW2 + fy)) * OW2 + fx) * Cout + co] = F2BF(v);
        s1 += v; s2 += v * v;
    }
}

// ---- k_conv4 v8: round-7/8 verified structure + occupancy 4 blocks/CU ----
__global__ __launch_bounds__(256, 4) void k_conv4(const __hip_bfloat16* __restrict__ in,
        const __hip_bfloat16* __restrict__ w4, __hip_bfloat16* __restrict__ out,
        int inH, int inW, int Cout, float* __restrict__ s1o, float* __restrict__ s2o,
        const float* __restrict__ bnS1, const float* __restrict__ bnS2,
        const void* __restrict__ g, const void* __restrict__ bb, float invN,
        const void* __restrict__ img) {
    int Cout4 = Cout << 2;
    int csh = (Cout == 512) ? 9 : 8;
    int G = Cout4 >> 5;
    int tXn = inW >> 4, tYn = inH >> 3;
    int bid = blockIdx.y;
    int tX = bid % tXn; int tmp = bid / tXn; int tY = tmp % tYn; int b = tmp / tYn;
    int co0 = blockIdx.x * 128;
    __shared__ __align__(16) __hip_bfloat16 Hs[4 * 1448];
    __shared__ float scT[512], shT[512];
    int tid = threadIdx.x;
    int l = tid & 63, l31 = l & 31, hi = l >> 5;
    int wave = tid >> 6;
    int dobn = (bnS1 != nullptr);
    if (dobn) {
        int isbf = detect_bf(img);
        for (int c = tid; c < 512; c += 256) {
            float m = bnS1[c] * invN, var = bnS2[c] * invN - m * m;
            float sc = inp(g, c, isbf) * rsqrtf(var + 1e-5f);
            scT[c] = sc; shT[c] = inp(bb, c, isbf) - m * sc;
        }
    }
    int R0 = (tY << 3) - 1, C0 = (tX << 4) - 1;
    long base = (long)b * inH * inW;
    int sub = tid & 3;
    const __hip_bfloat16* ga[3];
    int wo[3];
#pragma unroll
    for (int s = 0; s < 3; ++s) {
        int gi = tid + s * 256;
        int p = gi >> 2; if (p > 179) p = 179;
        int hy = p / 18, hx = p - hy * 18;
        int gr = R0 + hy; gr = gr < 0 ? 0 : (gr > inH - 1 ? inH - 1 : gr);
        int gc = C0 + hx; gc = gc < 0 ? 0 : (gc > inW - 1 ? inW - 1 : gc);
        ga[s] = in + (base + (long)gr * inW + gc) * 512 + sub * 8;
        wo[s] = sub * 1448 + p * 8;
    }
    int has2 = (tid < 208);
    short8 r0 = *(const short8*)(ga[0]);
    short8 r1 = *(const short8*)(ga[1]);
    short8 r2 = {0, 0, 0, 0, 0, 0, 0, 0};
    if (has2) r2 = *(const short8*)(ga[2]);
    int qA = hi * 1448;
    int qB = qA + 2896;
    int h[4];
#pragma unroll
    for (int i = 0; i < 4; ++i) {
        int px = i * 32 + l31;
        h[i] = ((px >> 4) * 18 + (px & 15)) * 8;
    }
    const __hip_bfloat16* wl2 = w4 + (long)l * 8;
    int cgw = (co0 >> 5) + wave;
    short8 wS0[2], wS1[2], wS2[2];
#define LDW(S, t, c) { long fb = (((long)((t) * 16 + (c)) * G + cgw) * 2) * 512; \
    S[0] = *(const short8*)(wl2 + fb); \
    S[1] = *(const short8*)(wl2 + fb + 512); }
    floatx16 zero16 = {0,0,0,0,0,0,0,0,0,0,0,0,0,0,0,0};
    floatx16 a[4];
#pragma unroll
    for (int i = 0; i < 4; ++i) a[i] = zero16;
    LDW(wS0, 0, 0);
    for (int ci0 = 0; ci0 < 512; ci0 += 32) {
        int cc = ci0 >> 5;
        __syncthreads();
        if (dobn) {
            float scv[8], shv[8];
#pragma unroll
            for (int k = 0; k < 8; ++k) { int c = ci0 + sub * 8 + k; scv[k] = scT[c]; shv[k] = shT[c]; }
#pragma unroll
            for (int k = 0; k < 8; ++k) {
                float f0 = bfbits2f(r0[k]) * scv[k] + shv[k]; r0[k] = f2bfbits(f0 > 0.f ? f0 : 0.f);
                float f1 = bfbits2f(r1[k]) * scv[k] + shv[k]; r1[k] = f2bfbits(f1 > 0.f ? f1 : 0.f);
                float f2 = bfbits2f(r2[k]) * scv[k] + shv[k]; r2[k] = f2bfbits(f2 > 0.f ? f2 : 0.f);
            }
        }
        *(short8*)(Hs + wo[0]) = r0;
        *(short8*)(Hs + wo[1]) = r1;
        if (has2) *(short8*)(Hs + wo[2]) = r2;
        __syncthreads();
        if (ci0 < 480) {
            r0 = *(const short8*)(ga[0] + ci0 + 32);
            r1 = *(const short8*)(ga[1] + ci0 + 32);
            if (has2) r2 = *(const short8*)(ga[2] + ci0 + 32);
        }
#pragma unroll
        for (int tap = 0; tap < 9; ++tap) {
            {
                int nt = tap + 1, ncc = cc;
                if (nt == 9) { nt = 0; ncc = cc + 1; }
                if (ncc < 16) {
                    if (((tap + 1) % 3) == 0)      { LDW(wS0, nt, ncc); }
                    else if (((tap + 1) % 3) == 1) { LDW(wS1, nt, ncc); }
                    else                            { LDW(wS2, nt, ncc); }
                }
            }
            int dy = tap / 3, dx = tap - dy * 3;
            int hoE = (dy * 18 + dx) * 8;
            if ((tap % 3) == 0) {
#pragma unroll
                for (int i = 0; i < 4; ++i) {
                    short8 af0 = *(const short8*)(Hs + qA + h[i] + hoE);
                    short8 af1 = *(const short8*)(Hs + qB + h[i] + hoE);
                    a[i] = __builtin_amdgcn_mfma_f32_32x32x16_bf16(af0, wS0[0], a[i], 0, 0, 0);
                    a[i] = __builtin_amdgcn_mfma_f32_32x32x16_bf16(af1, wS0[1], a[i], 0, 0, 0);
                }
            } else if ((tap % 3) == 1) {
#pragma unroll
                for (int i = 0; i < 4; ++i) {
                    short8 af0 = *(const short8*)(Hs + qA + h[i] + hoE);
                    short8 af1 = *(const short8*)(Hs + qB + h[i] + hoE);
                    a[i] = __builtin_amdgcn_mfma_f32_32x32x16_bf16(af0, wS1[0], a[i], 0, 0, 0);
                    a[i] = __builtin_amdgcn_mfma_f32_32x32x16_bf16(af1, wS1[1], a[i], 0, 0, 0);
                }
            } else {
#pragma unroll
                for (int i = 0; i < 4; ++i) {
                    short8 af0 = *(const short8*)(Hs + qA + h[i] + hoE);
                    short8 af1 = *(const short8*)(Hs + qB + h[i] + hoE);
                    a[i] = __builtin_amdgcn_mfma_f32_32x32x16_bf16(af0, wS2[0], a[i], 0, 0, 0);
                    a[i] = __builtin_amdgcn_mfma_f32_32x32x16_bf16(af1, wS2[1], a[i], 0, 0, 0);
                }
            }
        }
    }
#undef LDW
    int OW2 = inW << 1;
    float s1v = 0.f, s2v = 0.f;
    int co4w = co0 + wave * 32 + l31;
#pragma unroll
    for (int i = 0; i < 4; ++i)
        epi32(a[i], i * 32, co4w, csh, Cout, tY, tX, b, OW2, hi, out, s1v, s2v);
    s1v += __shfl_xor(s1v, 32); s2v += __shfl_xor(s2v, 32);
    if (hi == 0) {
        int ch = co4w & (Cout - 1);
        atomicAdd(s1o + ch, s1v);
        atomicAdd(s2o + ch, s2v);
    }
}

// ---- k_efix: boundary repair (16x16 MFMA path, unchanged semantics) ----
__global__ __launch_bounds__(256) void k_efix(const __hip_bfloat16* __restrict__ in,
        __hip_bfloat16* __restrict__ Y, const __hip_bfloat16* __restrict__ wRo,
        int inW, int Cout, int ebase,
        float* __restrict__ s1o, float* __restrict__ s2o) {
    int OW = inW << 1;
    int coT = Cout >> 6;
    int b = blockIdx.x / coT, cot = blockIdx.x - b * coT;
    int co0 = cot << 6;
    int e = ebase + blockIdx.y;   // 0 top, 1 bottom, 2 left, 3 right
    __shared__ __align__(16) __hip_bfloat16 E[130 * 40];
    __shared__ __align__(16) __hip_bfloat16 Lline[64 * 32];
    int tid = threadIdx.x;
    int wave = tid >> 6, l = tid & 63, lm = l & 15, q = l >> 4;
    int mspan = OW >> 2;
    int ilim = OW >> 6;
    int mb = wave * mspan;
    floatx4 zero4 = {0.f, 0.f, 0.f, 0.f};
    floatx4 acc[2][4];
    for (int i = 0; i < 2; ++i) for (int j = 0; j < 4; ++j) acc[i][j] = zero4;
    int lineG = inW * 4;
    int eG = (OW + 2) * 4;
    int haveL = (tid < lineG);
    const __hip_bfloat16* lbase = in;
    {
        int x = tid >> 2, sb = tid & 3;
        long gidx;
        if (e < 2) { int R = (e == 0) ? 0 : inW - 1; gidx = (long)(b * inW + R) * inW + x; }
        else       { int Cc = (e == 2) ? 0 : inW - 1; gidx = (long)(b * inW + x) * inW + Cc; }
        if (x >= inW) gidx = (long)b * inW * inW;
        lbase = in + gidx * 512 + sb * 8;
    }
    short8 rl = {0, 0, 0, 0, 0, 0, 0, 0};
    if (haveL) rl = *(const short8*)(lbase);
    for (int ci0 = 0; ci0 < 512; ci0 += 32) {
        __syncthreads();
        if (haveL) *(short8*)(Lline + tid * 8) = rl;
        __syncthreads();
        if (ci0 < 480 && haveL) rl = *(const short8*)(lbase + ci0 + 32);
        for (int t = tid; t < eG; t += 256) {
            int f1 = t >> 2, sb = t & 3;
            int f = f1 - 1;
            short8 res = {0, 0, 0, 0, 0, 0, 0, 0};
            if (f < 0 || f >= OW) {
                if (e < 2) { int xx = (f < 0) ? 0 : inW - 1; res = *(const short8*)(Lline + (xx * 4 + sb) * 8); }
            } else {
                int x0; float w0;
                if (f & 1) { x0 = f >> 1; w0 = 0.75f; } else { x0 = (f >> 1) - 1; w0 = 0.25f; }
                int x1 = x0 + 1;
                if (x0 < 0) x0 = 0;
                if (x1 > inW - 1) x1 = inW - 1;
                short8 v0 = *(const short8*)(Lline + (x0 * 4 + sb) * 8);
                short8 v1 = *(const short8*)(Lline + (x1 * 4 + sb) * 8);
                float w1c = 1.f - w0;
#pragma unroll
                for (int k = 0; k < 8; ++k)
                    res[k] = f2bfbits(w0 * bfbits2f(v0[k]) + w1c * bfbits2f(v1[k]));
            }
            *(short8*)(E + f1 * 40 + sb * 8) = res;
        }
        __syncthreads();
        int cc = ci0 >> 5;
#pragma unroll
        for (int t = 0; t < 3; ++t) {
            int tap = (e == 0) ? t : (e == 1) ? (6 + t) : (e == 2) ? (t * 3) : (t * 3 + 2);
            short8 bfv[4];
#pragma unroll
            for (int j = 0; j < 4; ++j)
                bfv[j] = *(const short8*)(wRo + ((long)(tap * 16 + cc) * Cout + co0 + j * 16 + lm) * 32 + q * 8);
#pragma unroll
            for (int i = 0; i < 2; ++i) {
                if (i < ilim) {
                    short8 af = *(const short8*)(E + (mb + i * 16 + lm + t) * 40 + q * 8);
#pragma unroll
                    for (int j = 0; j < 4; ++j)
                        acc[i][j] = __builtin_amdgcn_mfma_f32_16x16x32_bf16(af, bfv[j], acc[i][j], 0, 0, 0);
                }
            }
        }
    }
    float d1s[4] = {0.f, 0.f, 0.f, 0.f}, d2s[4] = {0.f, 0.f, 0.f, 0.f};
    for (int i = 0; i < ilim; ++i)
#pragma unroll
    for (int j = 0; j < 4; ++j) {
        int co = co0 + j * 16 + lm;
#pragma unroll
        for (int r = 0; r < 4; ++r) {
            int m = mb + i * 16 + q * 4 + r;
            int fy, fx;
            if (e == 0) { fy = 0; fx = m; }
            else if (e == 1) { fy = OW - 1; fx = m; }
            else if (e == 2) { fy = m; fx = 0; }
            else { fy = m; fx = OW - 1; }
            long a = (((long)(b * OW + fy)) * OW + fx) * Cout + co;
            float vo = BF2F(Y[a]);
            float vn = vo - acc[i][j][r];
            Y[a] = F2BF(vn);
            d1s[j] += vn - vo;
            d2s[j] += vn * vn - vo * vo;
        }
    }
#pragma unroll
    for (int j = 0; j < 4; ++j) {
        d1s[j] += __shfl_xor(d1s[j], 16); d1s[j] += __shfl_xor(d1s[j], 32);
        d2s[j] += __shfl_xor(d2s[j], 16); d2s[j] += __shfl_xor(d2s[j], 32);
    }
    if (q == 0) {
#pragma unroll
        for (int j = 0; j < 4; ++j) {
            atomicAdd(s1o + co0 + j * 16 + lm, d1s[j]);
            atomicAdd(s2o + co0 + j * 16 + lm, d2s[j]);
        }
    }
}

// ---- masks ----
__global__ __launch_bounds__(256) void k_masks(const __hip_bfloat16* __restrict__ x2,
                                               const float* __restrict__ effw,
                                               const float* __restrict__ effb,
                                               const float* __restrict__ word2,
                                               void* __restrict__ mout,
                                               const float* __restrict__ s1,
                                               const float* __restrict__ s2,
                                               const void* __restrict__ g,
                                               const void* __restrict__ bb, float invN,
                                               const void* __restrict__ img) {
    int isbf = detect_bf(img);
    int bid = blockIdx.x;
    int tX = bid & 15, tY = (bid >> 4) & 15, b = bid >> 8;
    __shared__ __align__(16) __hip_bfloat16 H[100 * 264];
    __shared__ __align__(16) float EW[9 * 256];
    __shared__ float EB[9];
    __shared__ float sc2T[256];
    __shared__ float sh2T[256];
    int tid = threadIdx.x;
    {
        float m = s1[tid] * invN, var = s2[tid] * invN - m * m;
        float sc = inp(g, tid, isbf) * rsqrtf(var + 1e-5f);
        sc2T[tid] = sc; sh2T[tid] = inp(bb, tid, isbf) - m * sc;
    }
    __syncthreads();
    for (int e = tid; e < 3200; e += 256) {
        int c8 = e & 31, p = e >> 5;
        int hy = p / 10, hx = p - hy * 10;
        int gy = tY * 8 + hy - 1, gx = tX * 8 + hx - 1;
        short8 res = {0, 0, 0, 0, 0, 0, 0, 0};
        if (gy >= 0 && gy < 128 && gx >= 0 && gx < 128) {
            short8 raw = *(const short8*)(x2 + (((long)(b * 128 + gy)) * 128 + gx) * 256 + c8 * 8);
#pragma unroll
            for (int k = 0; k < 8; ++k) {
                int c = c8 * 8 + k;
                float v = bfbits2f(raw[k]) * sc2T[c] + sh2T[c];
                res[k] = f2bfbits(v > 0.f ? v : 0.f);
            }
        }
        *(short8*)(H + p * 264 + c8 * 8) = res;
    }
    for (int e = tid; e < 2304; e += 256) EW[e] = effw[b * 2304 + e];
    if (tid < 9) EB[tid] = effb[b * 9 + tid];
    __syncthreads();
    int px = tid & 63, part = tid >> 6;
    int py = px >> 3, pxc = px & 7;
    int cbase = part * 64;
    float acc = 0.f;
    for (int tap = 0; tap < 9; ++tap) {
        int ky = tap / 3, kx = tap - ky * 3;
        int hp = (py + ky) * 10 + pxc + kx;
        const __hip_bfloat16* hrow = H + (long)hp * 264 + cbase;
        const float* erow = EW + tap * 256 + cbase;
#pragma unroll
        for (int c8 = 0; c8 < 8; ++c8) {
            short8 h8 = *(const short8*)(hrow + c8 * 8);
            floatx4 e0 = *(const floatx4*)(erow + c8 * 8);
            floatx4 e1 = *(const floatx4*)(erow + c8 * 8 + 4);
            acc += bfbits2f(h8[0]) * e0[0] + bfbits2f(h8[1]) * e0[1] +
                   bfbits2f(h8[2]) * e0[2] + bfbits2f(h8[3]) * e0[3] +
                   bfbits2f(h8[4]) * e1[0] + bfbits2f(h8[5]) * e1[1] +
                   bfbits2f(h8[6]) * e1[2] + bfbits2f(h8[7]) * e1[3];
        }
    }
    float (*red)[64] = (float(*)[64])sc2T;
    red[part][px] = acc;
    __syncthreads();
    if (part == 0) {
        float s = red[0][px] + red[1][px] + red[2][px] + red[3][px];
        int oy = tY * 8 + py, ox = tX * 8 + pxc;
        float bias = word2[b * 2305 + 2304];
        for (int tap = 0; tap < 9; ++tap) {
            int ky = tap / 3, kx = tap - ky * 3;
            int iy = oy + ky - 1, ix = ox + kx - 1;
            if (iy >= 0 && iy < 128 && ix >= 0 && ix < 128) bias += EB[tap];
        }
        outw(mout, b * 16384 + oy * 128 + ox, s + bias, isbf);
    }
}

// ---- hid ----
__global__ void k_hid(const float* __restrict__ qa, const void* __restrict__ w1,
                      const void* __restrict__ b1, float* __restrict__ hid,
                      const void* __restrict__ img) {
    int isbf = detect_bf(img);
    int b = blockIdx.x, ht = blockIdx.y, tid = threadIdx.x;
    __shared__ float qL[1024];
    __shared__ float R[256];
    for (int j = tid; j < 1024; j += 256) qL[j] = qa[b * 1024 + j];
    __syncthreads();
    int h = ht * 64 + (tid >> 2), cl = tid & 3;
    float acc = 0.f;
#pragma unroll 4
    for (int k = 0; k < 256; ++k) {
        int c = cl + 4 * k;
        acc += qL[c] * inp(w1, (long)h * 1024 + c, isbf);
    }
    R[tid] = acc;
    __syncthreads();
    if (cl == 0) {
        float v = R[tid] + R[tid + 1] + R[tid + 2] + R[tid + 3] + inp(b1, h, isbf);
        hid[b * 256 + h] = v > 0.f ? v : 0.f;
    }
}

// ---- logits: PARALLEL form ----
__global__ void k_logits(const float* __restrict__ hid, const float* __restrict__ ansv,
                         const void* __restrict__ w2, const void* __restrict__ b2,
                         const void* __restrict__ lw2, const void* __restrict__ lb2,
                         const void* __restrict__ ew, const void* __restrict__ ebias,
                         void* __restrict__ out, const void* __restrict__ img) {
    int isbf = detect_bf(img);
    int b = blockIdx.x, tid = threadIdx.x;
    __shared__ float hidL[256], avL[512], gates[8], feat[128], dv[184];
    hidL[tid] = hid[b * 256 + tid];
    for (int j = tid; j < 512; j += 256) avL[j] = ansv[b * 512 + j];
    __syncthreads();
    {
        int e = tid >> 5, part = tid & 31;
        float ga = 0.f;
#pragma unroll
        for (int j = 0; j < 8; ++j)
            ga += hidL[part + j * 32] * inp(w2, e * 256 + part + j * 32, isbf);
        for (int off = 16; off; off >>= 1) ga += __shfl_xor(ga, off);
        if (part == 0) gates[e] = ga + inp(b2, e, isbf);
    }
    {
        int f = tid >> 1, half = tid & 1;
        float acc = 0.f;
#pragma unroll 4
        for (int k = 0; k < 256; ++k) {
            int c = half + 2 * k;
            acc += avL[c] * inp(lw2, (long)f * 512 + c, isbf);
        }
        acc += __shfl_xor(acc, 1);
        if (half == 0) feat[f] = acc + inp(lb2, f, isbf);
    }
    __syncthreads();
    if (tid == 0) {
        float mx = gates[0];
        for (int e = 1; e < 8; ++e) mx = fmaxf(mx, gates[e]);
        float z = 0.f;
        for (int e = 0; e < 8; ++e) { gates[e] = expf(gates[e] - mx); z += gates[e]; }
        for (int e = 0; e < 8; ++e) gates[e] /= z;
    }
    if (tid < 184) {
        int e = tid / 23, o = tid - e * 23;
        float d = inp(ebias, e * 23 + o, isbf);
#pragma unroll 4
        for (int ff = 0; ff < 128; ++ff)
            d += inp(ew, (long)(e * 23 + o) * 128 + ff, isbf) * feat[ff];
        dv[tid] = d;
    }
    __syncthreads();
    if (tid < 23) {
        float a = 0.f;
#pragma unroll
        for (int e = 0; e < 8; ++e) a += gates[e] * dv[e * 23 + tid];
        outw(out, OUT_LOGITS + b * 23 + tid, a, isbf);
    }
}

extern "C" void kernel_launch(void* const* d_in, const int* in_sizes, int n_in,
                              void* d_out, int out_size, void* d_ws, size_t ws_size,
                              hipStream_t stream) {
    (void)in_sizes; (void)n_in; (void)out_size; (void)ws_size;
    const void* img   = d_in[0];
    const void* state = d_in[2];
    const void* Wt    = d_in[4];
    const void* cw1   = d_in[7];
    const void* g1    = d_in[8];
    const void* bb1   = d_in[9];
    const void* cw2   = d_in[10];
    const void* g2    = d_in[11];
    const void* bb2   = d_in[12];
    const void* w3    = d_in[13];
    const void* b3    = d_in[14];
    const void* txtw  = d_in[15];
    const void* txtb  = d_in[16];
    const void* lnw   = d_in[17];
    const void* lnb   = d_in[18];
    const void* lnw2  = d_in[19];
    const void* lnb2  = d_in[20];
    const void* rw1   = d_in[21];
    const void* rb1   = d_in[22];
    const void* rw2   = d_in[23];
    const void* rb2   = d_in[24];
    const void* ew    = d_in[25];
    const void* eb    = d_in[26];

    char* ws = (char*)d_ws;
    __hip_bfloat16* W4R2 = (__hip_bfloat16*)(ws + WS_W4R2);
    __hip_bfloat16* WRO2 = (__hip_bfloat16*)(ws + WS_WRO2);
    __hip_bfloat16* WRO1 = (__hip_bfloat16*)(ws + WS_WRO1);
    __hip_bfloat16* Y1   = (__hip_bfloat16*)(ws + WS_Y1);
    __hip_bfloat16* Y2   = (__hip_bfloat16*)(ws + WS_Y2);
    __hip_bfloat16* W4R1 = (__hip_bfloat16*)(ws + WS_W4R1);
    __hip_bfloat16* A    = (__hip_bfloat16*)(ws + WS_A);
    __hip_bfloat16* WTB  = (__hip_bfloat16*)(ws + WS_WTB);
    __hip_bfloat16* SRCB = (__hip_bfloat16*)(ws + WS_SRCB);
    float* S1A = (float*)(ws + WS_STATS);
    float* S2A = S1A + 512;
    float* S1B = S1A + 1024;
    float* S2B = S1A + 1536;
    float* ANS   = (float*)(ws + WS_ANS);
    float* QA    = (float*)(ws + WS_QA);
    float* ANSV  = (float*)(ws + WS_ANSV);
    float* WORD  = (float*)(ws + WS_WORD);
    float* WORD2 = (float*)(ws + WS_WORD2);
    float* EFFW  = (float*)(ws + WS_EFFW);
    float* EFFB  = (float*)(ws + WS_EFFB);
    float* HID   = (float*)(ws + WS_HID);

    k_pre<<<5889, 256, 0, stream>>>(img, cw1, cw2, Wt, A, W4R1, W4R2, WRO1, WRO2, WTB,
                                    (float*)(ws + WS_STATS));
    k_gemm1<<<dim3(64, 4), 256, 0, stream>>>(A, WTB, SRCB, d_out, ANS, img);
    k_ansvec<<<dim3(8, 8), 256, 0, stream>>>(ANS, lnw, lnb, ANSV, img);
    k_word<<<8, 256, 0, stream>>>(ANSV, state, QA, WORD, img);
    k_txt<<<2305, 256, 0, stream>>>(WORD, txtw, txtb, WORD2, img);
    k_eff<<<72, 256, 0, stream>>>(WORD2, w3, b3, EFFW, EFFB, img);
    // conv1: composed at orig res 32x32 (128px x 128co4 blocks), Cout4=2048
    k_conv4<<<dim3(16, 64), 256, 0, stream>>>(SRCB, W4R1, Y1, 32, 32, 512, S1A, S2A,
                                              nullptr, nullptr, nullptr, nullptr, 0.f, img);
    k_efix<<<dim3(64, 2), 256, 0, stream>>>(SRCB, Y1, WRO1, 32, 512, 0, S1A, S2A);
    k_efix<<<dim3(64, 2), 256, 0, stream>>>(SRCB, Y1, WRO1, 32, 512, 2, S1A, S2A);
    // conv2: composed at orig res 64x64, Cout4=1024, bn1+relu fused into halo staging
    k_conv4<<<dim3(8, 256), 256, 0, stream>>>(Y1, W4R2, Y2, 64, 64, 256, S1B, S2B,
                                              S1A, S2A, g1, bb1, 1.f / 32768.f, img);
    k_efix<<<dim3(32, 2), 256, 0, stream>>>(Y1, Y2, WRO2, 64, 256, 0, S1B, S2B);
    k_efix<<<dim3(32, 2), 256, 0, stream>>>(Y1, Y2, WRO2, 64, 256, 2, S1B, S2B);
    k_masks<<<2048, 256, 0, stream>>>(Y2, EFFW, EFFB, WORD2, d_out,
                                      S1B, S2B, g2, bb2, 1.f / 131072.f, img);
    k_hid<<<dim3(8, 4), 256, 0, stream>>>(QA, rw1, rb1, HID, img);
    k_logits<<<8, 256, 0, stream>>>(HID, ANSV, rw2, rb2, lnw2, lnb2, ew, eb, d_out, img);
}